// Round 10
// baseline (986.239 us; speedup 1.0000x reference)
//
#include <hip/hip_runtime.h>
#include <stdint.h>

#define MEM 512
#define TAGD 100
#define WORD 300
#define TREE_DEPTH 14
#define LEAVES 16384
#define KLEAF 400
#define KP_LEAF 416
#define KCH 712
#define KP_CH 736
#define T2W 224   // tag_child(100) | tag_parent(100) | pad(24)
#define AP 72     // big3 A-LDS pitch
#define LP 136    // big2 LDS pitch

typedef __attribute__((ext_vector_type(8))) short short8;
typedef __attribute__((ext_vector_type(4))) float floatx4;

__device__ __forceinline__ float b2f(unsigned short u) {
    union { unsigned int i; float f; } v; v.i = ((unsigned int)u) << 16; return v.f;
}
__device__ __forceinline__ unsigned short f2b(float f) {
    union { float f; unsigned int i; } v; v.f = f;
    unsigned int r = v.i + 0x7FFFu + ((v.i >> 16) & 1u);
    return (unsigned short)(r >> 16);
}
__device__ __forceinline__ float sigm(float x) { return 1.0f / (1.0f + __expf(-x)); }
__device__ __forceinline__ float tanh_f(float x) { return 1.0f - 2.0f / (__expf(2.0f * x) + 1.0f); }

// ---------------- init / detect ----------------

__global__ void init_kernel(int* flag) {
    if (blockIdx.x == 0 && threadIdx.x == 0) *flag = 0;
}

// fp32-vs-bf16: fp32 read as u16 -> low halves hit exp=0xFF with p=1/256.
__global__ void detect_kernel(const unsigned short* __restrict__ embs_u,
                              int* __restrict__ flag) {
    int tid = blockIdx.x * blockDim.x + threadIdx.x;
    int nth = gridDim.x * blockDim.x;
    int found = 0;
    for (int i = tid; i < 1048576; i += nth) {
        if (((embs_u[i] >> 7) & 0xFF) == 0xFF) { found = 1; break; }
    }
    unsigned long long b = __ballot(found);
    if ((threadIdx.x & 63) == 0 && b != 0ULL) atomicOr(flag, 1);
}

__device__ __forceinline__ unsigned short ld_bf(int f, const void* p, int i) {
    return f ? f2b(((const float*)p)[i]) : ((const unsigned short*)p)[i];
}
__device__ __forceinline__ float ld_f32(int f, const void* p, int i) {
    return f ? ((const float*)p)[i] : b2f(((const unsigned short*)p)[i]);
}

// ---------------- fused prep ----------------

__global__ void prep_kernel(const int* __restrict__ flag,
                            const void* embs, const void* tags,
                            const void* leaf_Wi, const void* ch_Wi,
                            const void* ch_Wh, const void* node_Wh,
                            const void* lbi, const void* lbh,
                            const void* cbi, const void* cbh,
                            const void* nbi, const void* nbh,
                            unsigned short* __restrict__ Wl,
                            unsigned short* __restrict__ Wc,
                            unsigned short* __restrict__ Whc,
                            unsigned short* __restrict__ Whn,
                            float* __restrict__ biasf,
                            unsigned short* __restrict__ T2,
                            unsigned short* __restrict__ X) {
    int f = *flag;
    int tid = blockIdx.x * blockDim.x + threadIdx.x;
    int nth = gridDim.x * blockDim.x;
    for (int idx = tid; idx < 1536 * KP_LEAF; idx += nth) {
        int r = idx / KP_LEAF, c = idx % KP_LEAF;
        Wl[idx] = (c < KLEAF) ? ld_bf(f, leaf_Wi, r * KLEAF + c) : (unsigned short)0;
    }
    for (int idx = tid; idx < 1536 * KP_CH; idx += nth) {
        int r = idx / KP_CH, c = idx % KP_CH;
        Wc[idx] = (c < KCH) ? ld_bf(f, ch_Wi, r * KCH + c) : (unsigned short)0;
    }
    for (int idx = tid; idx < 1536 * MEM; idx += nth) Whc[idx] = ld_bf(f, ch_Wh, idx);
    for (int idx = tid; idx < 1536 * MEM; idx += nth) Whn[idx] = ld_bf(f, node_Wh, idx);
    for (int i = tid; i < 1536; i += nth) {
        biasf[i]            = ld_f32(f, lbi, i);
        biasf[1536 + i]     = ld_f32(f, lbh, i);
        biasf[2 * 1536 + i] = ld_f32(f, cbi, i);
        biasf[3 * 1536 + i] = ld_f32(f, cbh, i);
        biasf[4 * 1536 + i] = ld_f32(f, nbi, i);
        biasf[5 * 1536 + i] = ld_f32(f, nbh, i);
    }
    // T2 all levels: level lvl (n=2^lvl) rows [32768-4n, 32768-4n+2n)
    for (int idx = tid; idx < 32766 * T2W; idx += nth) {
        int r = idx / T2W, c = idx % T2W;
        int d = 32768 - r;
        int lvl = 30 - __clz(d - 1);
        int n = 1 << lvl;
        int i = r - (32768 - 4 * n);
        int half = (i >= n) ? 1 : 0;
        int ii = half ? (i - n) : i;
        int p = (n - 1) + ii;
        int child = 2 * p + 1 + half;
        unsigned short v;
        if (c < TAGD) v = ld_bf(f, tags, child * TAGD + c);
        else if (c < 2 * TAGD) v = ld_bf(f, tags, p * TAGD + (c - TAGD));
        else v = 0;
        T2[idx] = v;
    }
    for (int idx = tid; idx < LEAVES * KP_LEAF; idx += nth) {
        int i = idx / KP_LEAF, c = idx % KP_LEAF;
        unsigned short v;
        if (c < WORD) v = ld_bf(f, embs, i * WORD + c);
        else if (c < WORD + TAGD) v = ld_bf(f, tags, (LEAVES - 1 + i) * TAGD + (c - WORD));
        else v = 0;
        X[idx] = v;
    }
}

struct Chunk {
    const unsigned short* A; int astride; int alpha; int beta;
    const unsigned short* W; int wstride; int wkb; int len;
};

// ================= BIG3 (leaf + levels n>=2048) =================
// XCD-locality mapping: mb = bid % Nm, jblk = bid / Nm (Nm multiple of 8) so
// all 8 j-blocks of one A m-slice land on ONE XCD -> A fetched once per XCD.

template<int MODE>
__launch_bounds__(512, 3)
__global__ void big3(const unsigned short* __restrict__ states,
                     const unsigned short* __restrict__ T2l,
                     const unsigned short* __restrict__ Xleaf,
                     const unsigned short* __restrict__ Wl,
                     const unsigned short* __restrict__ Wc,
                     const unsigned short* __restrict__ Whc,
                     const unsigned short* __restrict__ Whn,
                     const unsigned short* __restrict__ h1b,
                     const float* __restrict__ h1f,
                     const unsigned short* __restrict__ h2b,
                     const float* __restrict__ h2f,
                     const float* __restrict__ biasf,
                     int n,
                     unsigned short* __restrict__ outb,
                     float* __restrict__ outf) {
    constexpr int NCH = (MODE == 0) ? 7 : (MODE == 1) ? 12 : (MODE == 2) ? 20 : 8;
    constexpr int NS  = (MODE == 2) ? 4 : 3;

    int tid = threadIdx.x;
    int w = tid >> 6, lane = tid & 63, l15 = lane & 15, quad = lane >> 4;
    int wm = w >> 2, wj = w & 3;
    int bid = blockIdx.x;
    int Nm = n >> 7;                 // n/128 m-blocks (multiple of 8 for n>=1024)
    int mb = bid % Nm, jblk = bid / Nm;
    int m_blk = mb * 128;
    int jb = jblk * 64;

    __shared__ unsigned short lA[2][128 * AP];

    const unsigned short* T2r = T2l + (size_t)n * T2W;

    auto getch = [&](int c) -> Chunk {
        if (MODE == 0) {
            return Chunk{Xleaf + c * 64, KP_LEAF, 1, 0, Wl, KP_LEAF, c * 64, (c < 6) ? 64 : 32};
        } else if (MODE == 1) {
            if (c < 8) return Chunk{states + c * 64, MEM, 2, 2 * n - 1, Wc, KP_CH, c * 64, 64};
            int kb = (c - 8) * 64;
            return Chunk{T2l + kb, T2W, 1, 0, Wc, KP_CH, 512 + kb, (c < 11) ? 64 : 32};
        } else if (MODE == 2) {
            if (c < 8) return Chunk{states + c * 64, MEM, 2, 2 * n, Wc, KP_CH, c * 64, 64};
            if (c < 12) {
                int kb = (c - 8) * 64;
                return Chunk{T2r + kb, T2W, 1, 0, Wc, KP_CH, 512 + kb, (c < 11) ? 64 : 32};
            }
            int kb = (c - 12) * 64;
            return Chunk{h1b + kb, MEM, 1, 0, Whc, MEM, kb, 64};
        } else {
            return Chunk{h2b + c * 64, MEM, 1, 0, Whn, MEM, c * 64, 64};
        }
    };

    auto stageA = [&](Chunk k, int buf) {
        if (k.len == 64) {
#pragma unroll
            for (int p = 0; p < 2; p++) {
                int idx = tid + p * 512;
                int row = idx >> 3, gr = idx & 7;
                short8 v = *(const short8*)(k.A +
                    (size_t)(k.alpha * (m_blk + row) + k.beta) * k.astride + gr * 8);
                *(short8*)(&lA[buf][row * AP + gr * 8]) = v;
            }
        } else {
            int row = tid >> 2, gr = tid & 3;
            short8 v = *(const short8*)(k.A +
                (size_t)(k.alpha * (m_blk + row) + k.beta) * k.astride + gr * 8);
            *(short8*)(&lA[buf][row * AP + gr * 8]) = v;
        }
    };

    floatx4 acc[4][NS];
#pragma unroll
    for (int s = 0; s < 4; s++)
#pragma unroll
        for (int g = 0; g < NS; g++) acc[s][g] = (floatx4){0.f, 0.f, 0.f, 0.f};

    stageA(getch(0), 0);

#pragma unroll
    for (int c = 0; c < NCH; c++) {
        Chunk k = getch(c);
        __syncthreads();
        if (c + 1 < NCH) stageA(getch(c + 1), (c + 1) & 1);
        int wrow = jb + wj * 16 + l15;
        short8 wreg[2][3];
#pragma unroll
        for (int ki = 0; ki < 2; ki++) {
            if (ki * 32 < k.len) {
#pragma unroll
                for (int g = 0; g < 3; g++)
                    wreg[ki][g] = *(const short8*)(k.W +
                        (size_t)(g * 512 + wrow) * k.wstride + k.wkb + ki * 32 + quad * 8);
            }
        }
        const unsigned short* la = &lA[c & 1][(wm * 64 + l15) * AP + quad * 8];
#pragma unroll
        for (int ki = 0; ki < 2; ki++) {
            if (ki * 32 < k.len) {
                short8 a[4];
#pragma unroll
                for (int s = 0; s < 4; s++)
                    a[s] = *(const short8*)(la + s * 16 * AP + ki * 32);
#pragma unroll
                for (int s = 0; s < 4; s++)
                    acc[s][0] = __builtin_amdgcn_mfma_f32_16x16x32_bf16(a[s], wreg[ki][0], acc[s][0], 0, 0, 0);
#pragma unroll
                for (int s = 0; s < 4; s++)
                    acc[s][1] = __builtin_amdgcn_mfma_f32_16x16x32_bf16(a[s], wreg[ki][1], acc[s][1], 0, 0, 0);
                if (MODE == 2 && c >= 12) {
#pragma unroll
                    for (int s = 0; s < 4; s++)
                        acc[s][3] = __builtin_amdgcn_mfma_f32_16x16x32_bf16(a[s], wreg[ki][2], acc[s][3], 0, 0, 0);
                } else {
#pragma unroll
                    for (int s = 0; s < 4; s++)
                        acc[s][2] = __builtin_amdgcn_mfma_f32_16x16x32_bf16(a[s], wreg[ki][2], acc[s][2], 0, 0, 0);
                }
            }
        }
    }

    int j = jb + wj * 16 + l15;
    if (MODE == 0 || MODE == 1) {
        int bo = (MODE == 0) ? 0 : 3072;
        float bir = biasf[bo + j], biz = biasf[bo + 512 + j], bin = biasf[bo + 1024 + j];
        float bhr = biasf[bo + 1536 + j], bhz = biasf[bo + 2048 + j], bhn = biasf[bo + 2560 + j];
#pragma unroll
        for (int s = 0; s < 4; s++)
#pragma unroll
            for (int r = 0; r < 4; r++) {
                int m = m_blk + wm * 64 + s * 16 + quad * 4 + r;
                float rr = sigm(acc[s][0][r] + bir + bhr);
                float zz = sigm(acc[s][1][r] + biz + bhz);
                float nn = tanh_f(acc[s][2][r] + bin + rr * bhn);
                float h = (1.0f - zz) * nn;
                outb[(size_t)m * MEM + j] = f2b(h);
                if (MODE == 1 && outf) outf[(size_t)m * MEM + j] = h;
            }
    } else if (MODE == 2) {
        float bir = biasf[3072 + j], biz = biasf[3584 + j], bin = biasf[4096 + j];
        float bhr = biasf[4608 + j], bhz = biasf[5120 + j], bhn = biasf[5632 + j];
#pragma unroll
        for (int s = 0; s < 4; s++)
#pragma unroll
            for (int r = 0; r < 4; r++) {
                int m = m_blk + wm * 64 + s * 16 + quad * 4 + r;
                float hp = h1f ? h1f[(size_t)m * MEM + j] : b2f(h1b[(size_t)m * MEM + j]);
                float rr = sigm(acc[s][0][r] + bir + bhr);
                float zz = sigm(acc[s][1][r] + biz + bhz);
                float nn = tanh_f(acc[s][2][r] + bin + rr * (acc[s][3][r] + bhn));
                float h = (1.0f - zz) * nn + zz * hp;
                outb[(size_t)m * MEM + j] = f2b(h);
                if (outf) outf[(size_t)m * MEM + j] = h;
            }
    } else {
        float gir = biasf[6144 + j], giz = biasf[6656 + j], gin = biasf[7168 + j];
        float bhr = biasf[7680 + j], bhz = biasf[8192 + j], bhn = biasf[8704 + j];
#pragma unroll
        for (int s = 0; s < 4; s++)
#pragma unroll
            for (int r = 0; r < 4; r++) {
                int m = m_blk + wm * 64 + s * 16 + quad * 4 + r;
                float hp = h2f ? h2f[(size_t)m * MEM + j] : b2f(h2b[(size_t)m * MEM + j]);
                float rr = sigm(gir + acc[s][0][r] + bhr);
                float zz = sigm(giz + acc[s][1][r] + bhz);
                float nn = tanh_f(gin + rr * (acc[s][2][r] + bhn));
                float h = (1.0f - zz) * nn + zz * hp;
                outb[(size_t)m * MEM + j] = f2b(h);
            }
    }
}

// ================= BIG2 engine (mid levels 128..1024) =================
// Same XCD-locality mapping: mb = bid % Nm, j16 = bid / Nm.

template<int MODE, int SUBT>
__launch_bounds__(256, 2)
__global__ void big2(const unsigned short* __restrict__ states,
                     const unsigned short* __restrict__ T2l,
                     const unsigned short* __restrict__ Wc,
                     const unsigned short* __restrict__ Whc,
                     const unsigned short* __restrict__ Whn,
                     const unsigned short* __restrict__ h1b,
                     const float* __restrict__ h1f,
                     const unsigned short* __restrict__ h2b,
                     const float* __restrict__ h2f,
                     const float* __restrict__ biasf,
                     int n,
                     unsigned short* __restrict__ outb,
                     float* __restrict__ outf) {
    constexpr int NCH = (MODE == 1) ? 6 : (MODE == 2) ? 10 : 4;
    constexpr int NS  = (MODE == 2) ? 4 : 3;

    int tid = threadIdx.x;
    int w = tid >> 6, lane = tid & 63, l15 = lane & 15, quad = lane >> 4;
    int Nm = n / (64 * SUBT);
    int mb = blockIdx.x % Nm, j16 = blockIdx.x / Nm;
    int m_blk = mb * (64 * SUBT);
    int jb = j16 * 16;
    int mw = m_blk + w * 16 * SUBT;

    __shared__ unsigned short lds[2][48 * LP];

    const unsigned short* T2r = T2l + (size_t)n * T2W;

    auto getch = [&](int c) -> Chunk {
        if (MODE == 1) {
            if (c < 4) return Chunk{states + c * 128, MEM, 2, 2 * n - 1, Wc, KP_CH, c * 128, 128};
            if (c == 4) return Chunk{T2l, T2W, 1, 0, Wc, KP_CH, 512, 128};
            return Chunk{T2l + 128, T2W, 1, 0, Wc, KP_CH, 640, 96};
        } else if (MODE == 2) {
            if (c < 4) return Chunk{states + c * 128, MEM, 2, 2 * n, Wc, KP_CH, c * 128, 128};
            if (c == 4) return Chunk{T2r, T2W, 1, 0, Wc, KP_CH, 512, 128};
            if (c == 5) return Chunk{T2r + 128, T2W, 1, 0, Wc, KP_CH, 640, 96};
            int kb = (c - 6) * 128;
            return Chunk{h1b + kb, MEM, 1, 0, Whc, MEM, kb, 128};
        } else {
            int kb = c * 128;
            return Chunk{h2b + kb, MEM, 1, 0, Whn, MEM, kb, 128};
        }
    };

    auto stage = [&](Chunk k, int buf) {
        int gr = k.len >> 3;
        int kc = tid & 15;
#pragma unroll
        for (int p = 0; p < 3; p++) {
            int row = (tid >> 4) + p * 16;
            if (kc < gr) {
                int gate = row >> 4, jj = row & 15;
                short8 v = *(const short8*)(k.W + (size_t)(gate * 512 + jb + jj) * k.wstride + k.wkb + kc * 8);
                *(short8*)(&lds[buf][row * LP + kc * 8]) = v;
            }
        }
    };

    floatx4 acc[SUBT][NS];
#pragma unroll
    for (int s = 0; s < SUBT; s++)
#pragma unroll
        for (int g = 0; g < NS; g++) acc[s][g] = (floatx4){0.f, 0.f, 0.f, 0.f};

    stage(getch(0), 0);

#pragma unroll
    for (int c = 0; c < NCH; c++) {
        Chunk k = getch(c);
        __syncthreads();
        if (c + 1 < NCH) stage(getch(c + 1), (c + 1) & 1);
        short8 areg[4][SUBT];
#pragma unroll
        for (int ki = 0; ki < 4; ki++) {
            if (ki * 32 < k.len) {
#pragma unroll
                for (int s = 0; s < SUBT; s++) {
                    areg[ki][s] = *(const short8*)(k.A +
                        (size_t)(k.alpha * (mw + s * 16 + l15) + k.beta) * k.astride +
                        quad * 8 + ki * 32);
                }
            }
        }
        const unsigned short* lb = &lds[c & 1][l15 * LP + quad * 8];
#pragma unroll
        for (int ki = 0; ki < 4; ki++) {
            if (ki * 32 < k.len) {
                short8 b0 = *(const short8*)(lb + ki * 32);
                short8 b1 = *(const short8*)(lb + 16 * LP + ki * 32);
                short8 b2 = *(const short8*)(lb + 32 * LP + ki * 32);
#pragma unroll
                for (int s = 0; s < SUBT; s++)
                    acc[s][0] = __builtin_amdgcn_mfma_f32_16x16x32_bf16(areg[ki][s], b0, acc[s][0], 0, 0, 0);
#pragma unroll
                for (int s = 0; s < SUBT; s++)
                    acc[s][1] = __builtin_amdgcn_mfma_f32_16x16x32_bf16(areg[ki][s], b1, acc[s][1], 0, 0, 0);
                if (MODE == 2 && c >= 6) {
#pragma unroll
                    for (int s = 0; s < SUBT; s++)
                        acc[s][3] = __builtin_amdgcn_mfma_f32_16x16x32_bf16(areg[ki][s], b2, acc[s][3], 0, 0, 0);
                } else {
#pragma unroll
                    for (int s = 0; s < SUBT; s++)
                        acc[s][2] = __builtin_amdgcn_mfma_f32_16x16x32_bf16(areg[ki][s], b2, acc[s][2], 0, 0, 0);
                }
            }
        }
    }

    int j = jb + l15;
    if (MODE == 1) {
        float bir = biasf[3072 + j], biz = biasf[3584 + j], bin = biasf[4096 + j];
        float bhr = biasf[4608 + j], bhz = biasf[5120 + j], bhn = biasf[5632 + j];
#pragma unroll
        for (int s = 0; s < SUBT; s++)
#pragma unroll
            for (int r = 0; r < 4; r++) {
                int m = mw + s * 16 + quad * 4 + r;
                float rr = sigm(acc[s][0][r] + bir + bhr);
                float zz = sigm(acc[s][1][r] + biz + bhz);
                float nn = tanh_f(acc[s][2][r] + bin + rr * bhn);
                float h = (1.0f - zz) * nn;
                outb[(size_t)m * MEM + j] = f2b(h);
                if (outf) outf[(size_t)m * MEM + j] = h;
            }
    } else if (MODE == 2) {
        float bir = biasf[3072 + j], biz = biasf[3584 + j], bin = biasf[4096 + j];
        float bhr = biasf[4608 + j], bhz = biasf[5120 + j], bhn = biasf[5632 + j];
#pragma unroll
        for (int s = 0; s < SUBT; s++)
#pragma unroll
            for (int r = 0; r < 4; r++) {
                int m = mw + s * 16 + quad * 4 + r;
                float hp = h1f ? h1f[(size_t)m * MEM + j] : b2f(h1b[(size_t)m * MEM + j]);
                float rr = sigm(acc[s][0][r] + bir + bhr);
                float zz = sigm(acc[s][1][r] + biz + bhz);
                float nn = tanh_f(acc[s][2][r] + bin + rr * (acc[s][3][r] + bhn));
                float h = (1.0f - zz) * nn + zz * hp;
                outb[(size_t)m * MEM + j] = f2b(h);
                if (outf) outf[(size_t)m * MEM + j] = h;
            }
    } else {
        float gir = biasf[6144 + j], giz = biasf[6656 + j], gin = biasf[7168 + j];
        float bhr = biasf[7680 + j], bhz = biasf[8192 + j], bhn = biasf[8704 + j];
#pragma unroll
        for (int s = 0; s < SUBT; s++)
#pragma unroll
            for (int r = 0; r < 4; r++) {
                int m = mw + s * 16 + quad * 4 + r;
                float hp = h2f ? h2f[(size_t)m * MEM + j] : b2f(h2b[(size_t)m * MEM + j]);
                float rr = sigm(gir + acc[s][0][r] + bhr);
                float zz = sigm(giz + acc[s][1][r] + bhz);
                float nn = tanh_f(gin + rr * (acc[s][2][r] + bhn));
                float h = (1.0f - zz) * nn + zz * hp;
                outb[(size_t)m * MEM + j] = f2b(h);
            }
    }
}

// ================= SMALL-LEVEL KERNELS (r3-proven, levels n<=64) =================

__launch_bounds__(256)
__global__ void gemm_stage1(const unsigned short* __restrict__ states,
                            const unsigned short* __restrict__ T2,
                            const unsigned short* __restrict__ Wi,
                            const float* __restrict__ biasf,
                            int n,
                            unsigned short* __restrict__ h1b,
                            float* __restrict__ h1f) {
    int wv = threadIdx.x >> 6, lane = threadIdx.x & 63;
    int l15 = lane & 15, quad = lane >> 4, koff = quad * 8;
    int m_blk = blockIdx.x * 64;
    int jb = blockIdx.y * 64 + wv * 16;

    floatx4 acc[4][3];
#pragma unroll
    for (int s = 0; s < 4; s++)
#pragma unroll
        for (int g = 0; g < 3; g++) acc[s][g] = (floatx4){0.f, 0.f, 0.f, 0.f};
    short8 z8 = {0, 0, 0, 0, 0, 0, 0, 0};

    for (int kb = 0; kb < KP_CH; kb += 32) {
        int k0 = kb + koff;
        short8 a[4];
#pragma unroll
        for (int s = 0; s < 4; s++) {
            int row = m_blk + s * 16 + l15;
            if (row >= n) a[s] = z8;
            else if (kb < 512)
                a[s] = *(const short8*)(states + (size_t)(2 * n - 1 + 2 * row) * MEM + k0);
            else
                a[s] = *(const short8*)(T2 + (size_t)row * T2W + (k0 - 512));
        }
        short8 b[3];
#pragma unroll
        for (int g = 0; g < 3; g++)
            b[g] = *(const short8*)(Wi + (size_t)(jb + l15 + g * 512) * KP_CH + k0);
#pragma unroll
        for (int s = 0; s < 4; s++)
#pragma unroll
            for (int g = 0; g < 3; g++)
                acc[s][g] = __builtin_amdgcn_mfma_f32_16x16x32_bf16(a[s], b[g], acc[s][g], 0, 0, 0);
    }

    int j = jb + l15;
    float bir = biasf[3072 + j], biz = biasf[3584 + j], bin = biasf[4096 + j];
    float bhr = biasf[4608 + j], bhz = biasf[5120 + j], bhn = biasf[5632 + j];
#pragma unroll
    for (int s = 0; s < 4; s++)
#pragma unroll
        for (int r = 0; r < 4; r++) {
            int m = m_blk + s * 16 + quad * 4 + r;
            if (m >= n) continue;
            float rr = sigm(acc[s][0][r] + bir + bhr);
            float zz = sigm(acc[s][1][r] + biz + bhz);
            float nn = tanh_f(acc[s][2][r] + bin + rr * bhn);
            float h = (1.0f - zz) * nn;
            h1b[(size_t)m * MEM + j] = f2b(h);
            if (h1f) h1f[(size_t)m * MEM + j] = h;
        }
}

__launch_bounds__(256)
__global__ void gemm_stage2(const unsigned short* __restrict__ states,
                            const unsigned short* __restrict__ T2,
                            const unsigned short* __restrict__ Wi,
                            const unsigned short* __restrict__ h1b,
                            const float* __restrict__ h1f,
                            const unsigned short* __restrict__ Wh,
                            const float* __restrict__ biasf,
                            int n,
                            unsigned short* __restrict__ h2b,
                            float* __restrict__ h2f) {
    int wv = threadIdx.x >> 6, lane = threadIdx.x & 63;
    int l15 = lane & 15, quad = lane >> 4, koff = quad * 8;
    int m_blk = blockIdx.x * 64;
    int jb = blockIdx.y * 64 + wv * 16;

    floatx4 gi[4][3], gh[4][3];
#pragma unroll
    for (int s = 0; s < 4; s++)
#pragma unroll
        for (int g = 0; g < 3; g++) {
            gi[s][g] = (floatx4){0.f, 0.f, 0.f, 0.f};
            gh[s][g] = (floatx4){0.f, 0.f, 0.f, 0.f};
        }
    short8 z8 = {0, 0, 0, 0, 0, 0, 0, 0};

    for (int kb = 0; kb < KP_CH; kb += 32) {
        int k0 = kb + koff;
        short8 a[4];
#pragma unroll
        for (int s = 0; s < 4; s++) {
            int row = m_blk + s * 16 + l15;
            if (row >= n) a[s] = z8;
            else if (kb < 512)
                a[s] = *(const short8*)(states + (size_t)(2 * n + 2 * row) * MEM + k0);
            else
                a[s] = *(const short8*)(T2 + (size_t)(n + row) * T2W + (k0 - 512));
        }
        short8 b[3];
#pragma unroll
        for (int g = 0; g < 3; g++)
            b[g] = *(const short8*)(Wi + (size_t)(jb + l15 + g * 512) * KP_CH + k0);
#pragma unroll
        for (int s = 0; s < 4; s++)
#pragma unroll
            for (int g = 0; g < 3; g++)
                gi[s][g] = __builtin_amdgcn_mfma_f32_16x16x32_bf16(a[s], b[g], gi[s][g], 0, 0, 0);
    }

    for (int kb = 0; kb < MEM; kb += 32) {
        int k0 = kb + koff;
        short8 a[4];
#pragma unroll
        for (int s = 0; s < 4; s++) {
            int row = m_blk + s * 16 + l15;
            a[s] = (row < n) ? *(const short8*)(h1b + (size_t)row * MEM + k0) : z8;
        }
        short8 b[3];
#pragma unroll
        for (int g = 0; g < 3; g++)
            b[g] = *(const short8*)(Wh + (size_t)(jb + l15 + g * 512) * MEM + k0);
#pragma unroll
        for (int s = 0; s < 4; s++)
#pragma unroll
            for (int g = 0; g < 3; g++)
                gh[s][g] = __builtin_amdgcn_mfma_f32_16x16x32_bf16(a[s], b[g], gh[s][g], 0, 0, 0);
    }

    int j = jb + l15;
    float bir = biasf[3072 + j], biz = biasf[3584 + j], bin = biasf[4096 + j];
    float bhr = biasf[4608 + j], bhz = biasf[5120 + j], bhn = biasf[5632 + j];
#pragma unroll
    for (int s = 0; s < 4; s++)
#pragma unroll
        for (int r = 0; r < 4; r++) {
            int m = m_blk + s * 16 + quad * 4 + r;
            if (m >= n) continue;
            float hp = h1f ? h1f[(size_t)m * MEM + j] : b2f(h1b[(size_t)m * MEM + j]);
            float rr = sigm(gi[s][0][r] + bir + gh[s][0][r] + bhr);
            float zz = sigm(gi[s][1][r] + biz + gh[s][1][r] + bhz);
            float nn = tanh_f(gi[s][2][r] + bin + rr * (gh[s][2][r] + bhn));
            float h = (1.0f - zz) * nn + zz * hp;
            h2b[(size_t)m * MEM + j] = f2b(h);
            if (h2f) h2f[(size_t)m * MEM + j] = h;
        }
}

__launch_bounds__(256)
__global__ void gemm_stage3(const unsigned short* __restrict__ h2b,
                            const float* __restrict__ h2f,
                            const unsigned short* __restrict__ Wh,
                            const float* __restrict__ biasf,
                            int n,
                            unsigned short* __restrict__ out,
                            float* __restrict__ outf) {
    int wv = threadIdx.x >> 6, lane = threadIdx.x & 63;
    int l15 = lane & 15, quad = lane >> 4, koff = quad * 8;
    int m_blk = blockIdx.x * 64;
    int jb = blockIdx.y * 64 + wv * 16;

    floatx4 acc[4][3];
#pragma unroll
    for (int s = 0; s < 4; s++)
#pragma unroll
        for (int g = 0; g < 3; g++) acc[s][g] = (floatx4){0.f, 0.f, 0.f, 0.f};
    short8 z8 = {0, 0, 0, 0, 0, 0, 0, 0};

    for (int kb = 0; kb < MEM; kb += 32) {
        int k0 = kb + koff;
        short8 a[4];
#pragma unroll
        for (int s = 0; s < 4; s++) {
            int row = m_blk + s * 16 + l15;
            a[s] = (row < n) ? *(const short8*)(h2b + (size_t)row * MEM + k0) : z8;
        }
        short8 b[3];
#pragma unroll
        for (int g = 0; g < 3; g++)
            b[g] = *(const short8*)(Wh + (size_t)(jb + l15 + g * 512) * MEM + k0);
#pragma unroll
        for (int s = 0; s < 4; s++)
#pragma unroll
            for (int g = 0; g < 3; g++)
                acc[s][g] = __builtin_amdgcn_mfma_f32_16x16x32_bf16(a[s], b[g], acc[s][g], 0, 0, 0);
    }

    int j = jb + l15;
    float gir = biasf[6144 + j], giz = biasf[6656 + j], gin = biasf[7168 + j];
    float bhr = biasf[7680 + j], bhz = biasf[8192 + j], bhn = biasf[8704 + j];
#pragma unroll
    for (int s = 0; s < 4; s++)
#pragma unroll
        for (int r = 0; r < 4; r++) {
            int m = m_blk + s * 16 + quad * 4 + r;
            if (m >= n) continue;
            float hp = h2f ? h2f[(size_t)m * MEM + j] : b2f(h2b[(size_t)m * MEM + j]);
            float rr = sigm(gir + acc[s][0][r] + bhr);
            float zz = sigm(giz + acc[s][1][r] + bhz);
            float nn = tanh_f(gin + rr * (acc[s][2][r] + bhn));
            float h = (1.0f - zz) * nn + zz * hp;
            out[(size_t)m * MEM + j] = f2b(h);
            if (outf) outf[(size_t)m * MEM + j] = h;
        }
}

__global__ void copy_out_kernel(const int* __restrict__ flag,
                                const unsigned short* __restrict__ states,
                                const float* __restrict__ rootf,
                                void* __restrict__ out) {
    int j = threadIdx.x;
    if (j >= MEM) return;
    if (*flag) ((float*)out)[j] = rootf[j];
    else ((unsigned short*)out)[j] = states[j];
}

// ---------------- launch ----------------

extern "C" void kernel_launch(void* const* d_in, const int* in_sizes, int n_in,
                              void* d_out, int out_size, void* d_ws, size_t ws_size,
                              hipStream_t stream) {
    const void* embs    = d_in[0];
    const void* tags    = d_in[1];
    const void* leaf_Wi = d_in[2];
    const void* leaf_bi = d_in[4];
    const void* leaf_bh = d_in[5];
    const void* node_Wh = d_in[7];
    const void* node_bi = d_in[8];
    const void* node_bh = d_in[9];
    const void* ch_Wi   = d_in[10];
    const void* ch_Wh   = d_in[11];
    const void* ch_bi   = d_in[12];
    const void* ch_bh   = d_in[13];
    (void)in_sizes; (void)n_in; (void)out_size;

    char* ws = (char*)d_ws;
    const size_t o_flag   = 0;
    const size_t o_bias   = 256;
    const size_t o_Wl     = o_bias + 36864;
    const size_t o_Wc     = o_Wl + (size_t)1536 * KP_LEAF * 2;
    const size_t o_Whc    = o_Wc + (size_t)1536 * KP_CH * 2;
    const size_t o_Whn    = o_Whc + (size_t)1536 * MEM * 2;
    const size_t o_states = o_Whn + (size_t)1536 * MEM * 2;
    const size_t o_T2     = o_states + (size_t)32768 * MEM * 2;
    const size_t o_h1b    = o_T2 + (size_t)32768 * T2W * 2;
    const size_t o_h2b    = o_h1b + (size_t)8192 * MEM * 2;
    const size_t o_rootf  = o_h2b + (size_t)8192 * MEM * 2;
    const size_t o_h1f    = o_rootf + 2048;
    const size_t o_h2f    = o_h1f + (size_t)8192 * MEM * 4;
    const size_t NEED0    = o_h2f + (size_t)8192 * MEM * 4;   // ~105 MB

    bool tier0 = (ws_size >= NEED0);

    int*            flag   = (int*)(ws + o_flag);
    float*          biasf  = (float*)(ws + o_bias);
    unsigned short* Wl     = (unsigned short*)(ws + o_Wl);
    unsigned short* Wc     = (unsigned short*)(ws + o_Wc);
    unsigned short* Whc    = (unsigned short*)(ws + o_Whc);
    unsigned short* Whn    = (unsigned short*)(ws + o_Whn);
    unsigned short* states = (unsigned short*)(ws + o_states);
    unsigned short* T2all  = (unsigned short*)(ws + o_T2);
    unsigned short* h1b    = (unsigned short*)(ws + o_h1b);
    unsigned short* h2b    = (unsigned short*)(ws + o_h2b);
    float*          rootf  = (float*)(ws + o_rootf);
    float*          h1f    = tier0 ? (float*)(ws + o_h1f) : nullptr;
    float*          h2f    = tier0 ? (float*)(ws + o_h2f) : nullptr;
    // Xleaf overlays h1b+h2b (dead before lvl-13 stage1)
    unsigned short* Xleaf  = (unsigned short*)(ws + o_h1b);

    init_kernel<<<1, 64, 0, stream>>>(flag);
    detect_kernel<<<256, 256, 0, stream>>>((const unsigned short*)embs, flag);
    prep_kernel<<<2048, 256, 0, stream>>>(flag, embs, tags,
                                          leaf_Wi, ch_Wi, ch_Wh, node_Wh,
                                          leaf_bi, leaf_bh, ch_bi, ch_bh,
                                          node_bi, node_bh,
                                          Wl, Wc, Whc, Whn, biasf, T2all, Xleaf);

    big3<0><<<(LEAVES / 128) * 8, 512, 0, stream>>>(
        states, T2all, Xleaf, Wl, Wc, Whc, Whn, h1b, h1f, h2b, h2f, biasf,
        LEAVES, states + (size_t)(LEAVES - 1) * MEM, nullptr);

#define LAUNCH_BIG3(M, OB, OF) \
    big3<M><<<(n / 128) * 8, 512, 0, stream>>>( \
        states, T2l, nullptr, Wl, Wc, Whc, Whn, h1b, h1f, h2b, h2f, biasf, n, OB, OF)
#define LAUNCH_BIG2(M, S, OB, OF) \
    big2<M, S><<<(n / (64 * S)) * 32, 256, 0, stream>>>( \
        states, T2l, Wc, Whc, Whn, h1b, h1f, h2b, h2f, biasf, n, OB, OF)

    for (int lvl = TREE_DEPTH - 1; lvl >= 0; lvl--) {
        int n = 1 << lvl;
        const unsigned short* T2l = T2all + (size_t)(32768 - 4 * n) * T2W;
        unsigned short* st_out = states + (size_t)(n - 1) * MEM;

        if (n >= 2048) {
            LAUNCH_BIG3(1, h1b, h1f);
            LAUNCH_BIG3(2, h2b, h2f);
            LAUNCH_BIG3(3, st_out, nullptr);
        } else if (n >= 1024) {
            LAUNCH_BIG2(1, 2, h1b, h1f);
            LAUNCH_BIG2(2, 2, h2b, h2f);
            LAUNCH_BIG2(3, 2, st_out, nullptr);
        } else if (n >= 128) {
            LAUNCH_BIG2(1, 1, h1b, h1f);
            LAUNCH_BIG2(2, 1, h2b, h2f);
            LAUNCH_BIG2(3, 1, st_out, nullptr);
        } else {
            dim3 g((n + 63) / 64, 8);
            gemm_stage1<<<g, 256, 0, stream>>>(states, T2l, Wc, biasf, n, h1b, h1f);
            gemm_stage2<<<g, 256, 0, stream>>>(states, T2l, Wc, h1b, h1f, Whc, biasf,
                                               n, h2b, h2f);
            gemm_stage3<<<g, 256, 0, stream>>>(h2b, h2f, Whn, biasf, n, st_out,
                                               (n == 1) ? rootf : nullptr);
        }
    }

    copy_out_kernel<<<1, 512, 0, stream>>>(flag, states, rootf, d_out);
}

// Round 11
// 928.509 us; speedup vs baseline: 1.0622x; 1.0622x over previous
//
#include <hip/hip_runtime.h>
#include <stdint.h>

#define MEM 512
#define TAGD 100
#define WORD 300
#define TREE_DEPTH 14
#define LEAVES 16384
#define KLEAF 400
#define KP_LEAF 416
#define KCH 712
#define KP_CH 736
#define T2W 224   // tag_child(100) | tag_parent(100) | pad(24)
#define AP 72     // big3 A-LDS pitch
#define LP 136    // big2 LDS pitch

typedef __attribute__((ext_vector_type(8))) short short8;
typedef __attribute__((ext_vector_type(4))) float floatx4;

__device__ __forceinline__ float b2f(unsigned short u) {
    union { unsigned int i; float f; } v; v.i = ((unsigned int)u) << 16; return v.f;
}
__device__ __forceinline__ unsigned short f2b(float f) {
    union { float f; unsigned int i; } v; v.f = f;
    unsigned int r = v.i + 0x7FFFu + ((v.i >> 16) & 1u);
    return (unsigned short)(r >> 16);
}
__device__ __forceinline__ float sigm(float x) { return 1.0f / (1.0f + __expf(-x)); }
__device__ __forceinline__ float tanh_f(float x) { return 1.0f - 2.0f / (__expf(2.0f * x) + 1.0f); }

// ---------------- init / detect ----------------

__global__ void init_kernel(int* flag) {
    if (blockIdx.x == 0 && threadIdx.x == 0) *flag = 0;
}

__global__ void detect_kernel(const unsigned short* __restrict__ embs_u,
                              int* __restrict__ flag) {
    int tid = blockIdx.x * blockDim.x + threadIdx.x;
    int nth = gridDim.x * blockDim.x;
    int found = 0;
    for (int i = tid; i < 1048576; i += nth) {
        if (((embs_u[i] >> 7) & 0xFF) == 0xFF) { found = 1; break; }
    }
    unsigned long long b = __ballot(found);
    if ((threadIdx.x & 63) == 0 && b != 0ULL) atomicOr(flag, 1);
}

__device__ __forceinline__ unsigned short ld_bf(int f, const void* p, int i) {
    return f ? f2b(((const float*)p)[i]) : ((const unsigned short*)p)[i];
}
__device__ __forceinline__ float ld_f32(int f, const void* p, int i) {
    return f ? ((const float*)p)[i] : b2f(((const unsigned short*)p)[i]);
}

// ---------------- fused prep ----------------

__global__ void prep_kernel(const int* __restrict__ flag,
                            const void* embs, const void* tags,
                            const void* leaf_Wi, const void* ch_Wi,
                            const void* ch_Wh, const void* node_Wh,
                            const void* lbi, const void* lbh,
                            const void* cbi, const void* cbh,
                            const void* nbi, const void* nbh,
                            unsigned short* __restrict__ Wl,
                            unsigned short* __restrict__ Wc,
                            unsigned short* __restrict__ Whc,
                            unsigned short* __restrict__ Whn,
                            float* __restrict__ biasf,
                            unsigned short* __restrict__ T2,
                            unsigned short* __restrict__ X) {
    int f = *flag;
    int tid = blockIdx.x * blockDim.x + threadIdx.x;
    int nth = gridDim.x * blockDim.x;
    for (int idx = tid; idx < 1536 * KP_LEAF; idx += nth) {
        int r = idx / KP_LEAF, c = idx % KP_LEAF;
        Wl[idx] = (c < KLEAF) ? ld_bf(f, leaf_Wi, r * KLEAF + c) : (unsigned short)0;
    }
    for (int idx = tid; idx < 1536 * KP_CH; idx += nth) {
        int r = idx / KP_CH, c = idx % KP_CH;
        Wc[idx] = (c < KCH) ? ld_bf(f, ch_Wi, r * KCH + c) : (unsigned short)0;
    }
    for (int idx = tid; idx < 1536 * MEM; idx += nth) Whc[idx] = ld_bf(f, ch_Wh, idx);
    for (int idx = tid; idx < 1536 * MEM; idx += nth) Whn[idx] = ld_bf(f, node_Wh, idx);
    for (int i = tid; i < 1536; i += nth) {
        biasf[i]            = ld_f32(f, lbi, i);
        biasf[1536 + i]     = ld_f32(f, lbh, i);
        biasf[2 * 1536 + i] = ld_f32(f, cbi, i);
        biasf[3 * 1536 + i] = ld_f32(f, cbh, i);
        biasf[4 * 1536 + i] = ld_f32(f, nbi, i);
        biasf[5 * 1536 + i] = ld_f32(f, nbh, i);
    }
    // T2 all levels: level lvl (n=2^lvl) rows [32768-4n, 32768-4n+2n)
    for (int idx = tid; idx < 32766 * T2W; idx += nth) {
        int r = idx / T2W, c = idx % T2W;
        int d = 32768 - r;
        int lvl = 30 - __clz(d - 1);
        int n = 1 << lvl;
        int i = r - (32768 - 4 * n);
        int half = (i >= n) ? 1 : 0;
        int ii = half ? (i - n) : i;
        int p = (n - 1) + ii;
        int child = 2 * p + 1 + half;
        unsigned short v;
        if (c < TAGD) v = ld_bf(f, tags, child * TAGD + c);
        else if (c < 2 * TAGD) v = ld_bf(f, tags, p * TAGD + (c - TAGD));
        else v = 0;
        T2[idx] = v;
    }
    for (int idx = tid; idx < LEAVES * KP_LEAF; idx += nth) {
        int i = idx / KP_LEAF, c = idx % KP_LEAF;
        unsigned short v;
        if (c < WORD) v = ld_bf(f, embs, i * WORD + c);
        else if (c < WORD + TAGD) v = ld_bf(f, tags, (LEAVES - 1 + i) * TAGD + (c - WORD));
        else v = 0;
        X[idx] = v;
    }
}

struct Chunk {
    const unsigned short* A; int astride; int alpha; int beta;
    const unsigned short* W; int wstride; int wkb; int len;
};

// ================= BIG3 v2 (leaf + levels n>=2048) =================
// 256 thr / 4 j-waves; tile 64m x 64j x 3 gates; wave = 64m x 16j.
// A->LDS dbuf (18.4 KB) shared by the 4 j-waves; W direct global.
// Supergroup swizzle: 8 j-readers of one m-slice have bids <=56 apart AND
// all == (mod 8) -> temporally adjacent on one XCD (A+W stay L2-resident).

template<int MODE>
__launch_bounds__(256, 4)
__global__ void big3(const unsigned short* __restrict__ states,
                     const unsigned short* __restrict__ T2l,
                     const unsigned short* __restrict__ Xleaf,
                     const unsigned short* __restrict__ Wl,
                     const unsigned short* __restrict__ Wc,
                     const unsigned short* __restrict__ Whc,
                     const unsigned short* __restrict__ Whn,
                     const unsigned short* __restrict__ h1b,
                     const float* __restrict__ h1f,
                     const unsigned short* __restrict__ h2b,
                     const float* __restrict__ h2f,
                     const float* __restrict__ biasf,
                     int n,
                     unsigned short* __restrict__ outb,
                     float* __restrict__ outf) {
    constexpr int NCH = (MODE == 0) ? 7 : (MODE == 1) ? 12 : (MODE == 2) ? 20 : 8;
    constexpr int NS  = (MODE == 2) ? 4 : 3;

    int tid = threadIdx.x;
    int w = tid >> 6, lane = tid & 63, l15 = lane & 15, quad = lane >> 4;
    int bid = blockIdx.x;
    // supergroup swizzle (Nm = n/64 is always a multiple of 8 here)
    int sg = bid >> 6;
    int mb = sg * 8 + (bid & 7);
    int jblk = (bid >> 3) & 7;
    int m_blk = mb * 64;
    int jb = jblk * 64;

    __shared__ unsigned short lA[2][64 * AP];

    const unsigned short* T2r = T2l + (size_t)n * T2W;

    auto getch = [&](int c) -> Chunk {
        if (MODE == 0) {
            return Chunk{Xleaf + c * 64, KP_LEAF, 1, 0, Wl, KP_LEAF, c * 64, (c < 6) ? 64 : 32};
        } else if (MODE == 1) {
            if (c < 8) return Chunk{states + c * 64, MEM, 2, 2 * n - 1, Wc, KP_CH, c * 64, 64};
            int kb = (c - 8) * 64;
            return Chunk{T2l + kb, T2W, 1, 0, Wc, KP_CH, 512 + kb, (c < 11) ? 64 : 32};
        } else if (MODE == 2) {
            if (c < 8) return Chunk{states + c * 64, MEM, 2, 2 * n, Wc, KP_CH, c * 64, 64};
            if (c < 12) {
                int kb = (c - 8) * 64;
                return Chunk{T2r + kb, T2W, 1, 0, Wc, KP_CH, 512 + kb, (c < 11) ? 64 : 32};
            }
            int kb = (c - 12) * 64;
            return Chunk{h1b + kb, MEM, 1, 0, Whc, MEM, kb, 64};
        } else {
            return Chunk{h2b + c * 64, MEM, 1, 0, Whn, MEM, c * 64, 64};
        }
    };

    auto stageA = [&](Chunk k, int buf) {
        if (k.len == 64) {
            // 64 rows x 8 granules = 512 slots, 2 per thread
#pragma unroll
            for (int p = 0; p < 2; p++) {
                int idx = tid + p * 256;
                int row = idx >> 3, gr = idx & 7;
                short8 v = *(const short8*)(k.A +
                    (size_t)(k.alpha * (m_blk + row) + k.beta) * k.astride + gr * 8);
                *(short8*)(&lA[buf][row * AP + gr * 8]) = v;
            }
        } else {
            // len 32: 64 x 4 = 256 slots
            int row = tid >> 2, gr = tid & 3;
            short8 v = *(const short8*)(k.A +
                (size_t)(k.alpha * (m_blk + row) + k.beta) * k.astride + gr * 8);
            *(short8*)(&lA[buf][row * AP + gr * 8]) = v;
        }
    };

    floatx4 acc[4][NS];
#pragma unroll
    for (int s = 0; s < 4; s++)
#pragma unroll
        for (int g = 0; g < NS; g++) acc[s][g] = (floatx4){0.f, 0.f, 0.f, 0.f};

    stageA(getch(0), 0);

#pragma unroll
    for (int c = 0; c < NCH; c++) {
        Chunk k = getch(c);
        __syncthreads();
        if (c + 1 < NCH) stageA(getch(c + 1), (c + 1) & 1);
        int wrow = jb + w * 16 + l15;
        short8 wreg[2][3];
#pragma unroll
        for (int ki = 0; ki < 2; ki++) {
            if (ki * 32 < k.len) {
#pragma unroll
                for (int g = 0; g < 3; g++)
                    wreg[ki][g] = *(const short8*)(k.W +
                        (size_t)(g * 512 + wrow) * k.wstride + k.wkb + ki * 32 + quad * 8);
            }
        }
        const unsigned short* la = &lA[c & 1][l15 * AP + quad * 8];
#pragma unroll
        for (int ki = 0; ki < 2; ki++) {
            if (ki * 32 < k.len) {
                short8 a[4];
#pragma unroll
                for (int s = 0; s < 4; s++)
                    a[s] = *(const short8*)(la + s * 16 * AP + ki * 32);
#pragma unroll
                for (int s = 0; s < 4; s++)
                    acc[s][0] = __builtin_amdgcn_mfma_f32_16x16x32_bf16(a[s], wreg[ki][0], acc[s][0], 0, 0, 0);
#pragma unroll
                for (int s = 0; s < 4; s++)
                    acc[s][1] = __builtin_amdgcn_mfma_f32_16x16x32_bf16(a[s], wreg[ki][1], acc[s][1], 0, 0, 0);
                if (MODE == 2 && c >= 12) {
#pragma unroll
                    for (int s = 0; s < 4; s++)
                        acc[s][3] = __builtin_amdgcn_mfma_f32_16x16x32_bf16(a[s], wreg[ki][2], acc[s][3], 0, 0, 0);
                } else {
#pragma unroll
                    for (int s = 0; s < 4; s++)
                        acc[s][2] = __builtin_amdgcn_mfma_f32_16x16x32_bf16(a[s], wreg[ki][2], acc[s][2], 0, 0, 0);
                }
            }
        }
    }

    int j = jb + w * 16 + l15;
    if (MODE == 0 || MODE == 1) {
        int bo = (MODE == 0) ? 0 : 3072;
        float bir = biasf[bo + j], biz = biasf[bo + 512 + j], bin = biasf[bo + 1024 + j];
        float bhr = biasf[bo + 1536 + j], bhz = biasf[bo + 2048 + j], bhn = biasf[bo + 2560 + j];
#pragma unroll
        for (int s = 0; s < 4; s++)
#pragma unroll
            for (int r = 0; r < 4; r++) {
                int m = m_blk + s * 16 + quad * 4 + r;
                float rr = sigm(acc[s][0][r] + bir + bhr);
                float zz = sigm(acc[s][1][r] + biz + bhz);
                float nn = tanh_f(acc[s][2][r] + bin + rr * bhn);
                float h = (1.0f - zz) * nn;
                outb[(size_t)m * MEM + j] = f2b(h);
                if (MODE == 1 && outf) outf[(size_t)m * MEM + j] = h;
            }
    } else if (MODE == 2) {
        float bir = biasf[3072 + j], biz = biasf[3584 + j], bin = biasf[4096 + j];
        float bhr = biasf[4608 + j], bhz = biasf[5120 + j], bhn = biasf[5632 + j];
#pragma unroll
        for (int s = 0; s < 4; s++)
#pragma unroll
            for (int r = 0; r < 4; r++) {
                int m = m_blk + s * 16 + quad * 4 + r;
                float hp = h1f ? h1f[(size_t)m * MEM + j] : b2f(h1b[(size_t)m * MEM + j]);
                float rr = sigm(acc[s][0][r] + bir + bhr);
                float zz = sigm(acc[s][1][r] + biz + bhz);
                float nn = tanh_f(acc[s][2][r] + bin + rr * (acc[s][3][r] + bhn));
                float h = (1.0f - zz) * nn + zz * hp;
                outb[(size_t)m * MEM + j] = f2b(h);
                if (outf) outf[(size_t)m * MEM + j] = h;
            }
    } else {
        float gir = biasf[6144 + j], giz = biasf[6656 + j], gin = biasf[7168 + j];
        float bhr = biasf[7680 + j], bhz = biasf[8192 + j], bhn = biasf[8704 + j];
#pragma unroll
        for (int s = 0; s < 4; s++)
#pragma unroll
            for (int r = 0; r < 4; r++) {
                int m = m_blk + s * 16 + quad * 4 + r;
                float hp = h2f ? h2f[(size_t)m * MEM + j] : b2f(h2b[(size_t)m * MEM + j]);
                float rr = sigm(gir + acc[s][0][r] + bhr);
                float zz = sigm(giz + acc[s][1][r] + bhz);
                float nn = tanh_f(gin + rr * (acc[s][2][r] + bhn));
                float h = (1.0f - zz) * nn + zz * hp;
                outb[(size_t)m * MEM + j] = f2b(h);
            }
    }
}

// ================= BIG2 engine (mid levels 128..1024, 64-row tiles) =================

template<int MODE>
__launch_bounds__(256, 2)
__global__ void big2(const unsigned short* __restrict__ states,
                     const unsigned short* __restrict__ T2l,
                     const unsigned short* __restrict__ Wc,
                     const unsigned short* __restrict__ Whc,
                     const unsigned short* __restrict__ Whn,
                     const unsigned short* __restrict__ h1b,
                     const float* __restrict__ h1f,
                     const unsigned short* __restrict__ h2b,
                     const float* __restrict__ h2f,
                     const float* __restrict__ biasf,
                     int n,
                     unsigned short* __restrict__ outb,
                     float* __restrict__ outf) {
    constexpr int NCH = (MODE == 1) ? 6 : (MODE == 2) ? 10 : 4;
    constexpr int NS  = (MODE == 2) ? 4 : 3;

    int tid = threadIdx.x;
    int w = tid >> 6, lane = tid & 63, l15 = lane & 15, quad = lane >> 4;
    int Nm = n >> 6;
    int bid = blockIdx.x;
    int mb, j16;
    if (Nm >= 8) {
        int sg = bid >> 6;
        int mSupers = Nm >> 3;
        mb  = (sg % mSupers) * 8 + (bid & 7);
        j16 = (sg / mSupers) * 8 + ((bid >> 3) & 7);
    } else {
        mb = bid % Nm; j16 = bid / Nm;
    }
    int m_blk = mb * 64;
    int jb = j16 * 16;
    int mw = m_blk + w * 16;

    __shared__ unsigned short lds[2][48 * LP];

    const unsigned short* T2r = T2l + (size_t)n * T2W;

    auto getch = [&](int c) -> Chunk {
        if (MODE == 1) {
            if (c < 4) return Chunk{states + c * 128, MEM, 2, 2 * n - 1, Wc, KP_CH, c * 128, 128};
            if (c == 4) return Chunk{T2l, T2W, 1, 0, Wc, KP_CH, 512, 128};
            return Chunk{T2l + 128, T2W, 1, 0, Wc, KP_CH, 640, 96};
        } else if (MODE == 2) {
            if (c < 4) return Chunk{states + c * 128, MEM, 2, 2 * n, Wc, KP_CH, c * 128, 128};
            if (c == 4) return Chunk{T2r, T2W, 1, 0, Wc, KP_CH, 512, 128};
            if (c == 5) return Chunk{T2r + 128, T2W, 1, 0, Wc, KP_CH, 640, 96};
            int kb = (c - 6) * 128;
            return Chunk{h1b + kb, MEM, 1, 0, Whc, MEM, kb, 128};
        } else {
            int kb = c * 128;
            return Chunk{h2b + kb, MEM, 1, 0, Whn, MEM, kb, 128};
        }
    };

    auto stage = [&](Chunk k, int buf) {
        int gr = k.len >> 3;
        int kc = tid & 15;
#pragma unroll
        for (int p = 0; p < 3; p++) {
            int row = (tid >> 4) + p * 16;
            if (kc < gr) {
                int gate = row >> 4, jj = row & 15;
                short8 v = *(const short8*)(k.W + (size_t)(gate * 512 + jb + jj) * k.wstride + k.wkb + kc * 8);
                *(short8*)(&lds[buf][row * LP + kc * 8]) = v;
            }
        }
    };

    floatx4 acc[NS];
#pragma unroll
    for (int g = 0; g < NS; g++) acc[g] = (floatx4){0.f, 0.f, 0.f, 0.f};

    stage(getch(0), 0);

#pragma unroll
    for (int c = 0; c < NCH; c++) {
        Chunk k = getch(c);
        __syncthreads();
        if (c + 1 < NCH) stage(getch(c + 1), (c + 1) & 1);
        short8 areg[4];
#pragma unroll
        for (int ki = 0; ki < 4; ki++) {
            if (ki * 32 < k.len) {
                areg[ki] = *(const short8*)(k.A +
                    (size_t)(k.alpha * (mw + l15) + k.beta) * k.astride +
                    quad * 8 + ki * 32);
            }
        }
        const unsigned short* lb = &lds[c & 1][l15 * LP + quad * 8];
#pragma unroll
        for (int ki = 0; ki < 4; ki++) {
            if (ki * 32 < k.len) {
                short8 b0 = *(const short8*)(lb + ki * 32);
                short8 b1 = *(const short8*)(lb + 16 * LP + ki * 32);
                short8 b2 = *(const short8*)(lb + 32 * LP + ki * 32);
                acc[0] = __builtin_amdgcn_mfma_f32_16x16x32_bf16(areg[ki], b0, acc[0], 0, 0, 0);
                acc[1] = __builtin_amdgcn_mfma_f32_16x16x32_bf16(areg[ki], b1, acc[1], 0, 0, 0);
                if (MODE == 2 && c >= 6)
                    acc[3] = __builtin_amdgcn_mfma_f32_16x16x32_bf16(areg[ki], b2, acc[3], 0, 0, 0);
                else
                    acc[2] = __builtin_amdgcn_mfma_f32_16x16x32_bf16(areg[ki], b2, acc[2], 0, 0, 0);
            }
        }
    }

    int j = jb + l15;
    if (MODE == 1) {
        float bir = biasf[3072 + j], biz = biasf[3584 + j], bin = biasf[4096 + j];
        float bhr = biasf[4608 + j], bhz = biasf[5120 + j], bhn = biasf[5632 + j];
#pragma unroll
        for (int r = 0; r < 4; r++) {
            int m = mw + quad * 4 + r;
            float rr = sigm(acc[0][r] + bir + bhr);
            float zz = sigm(acc[1][r] + biz + bhz);
            float nn = tanh_f(acc[2][r] + bin + rr * bhn);
            float h = (1.0f - zz) * nn;
            outb[(size_t)m * MEM + j] = f2b(h);
            if (outf) outf[(size_t)m * MEM + j] = h;
        }
    } else if (MODE == 2) {
        float bir = biasf[3072 + j], biz = biasf[3584 + j], bin = biasf[4096 + j];
        float bhr = biasf[4608 + j], bhz = biasf[5120 + j], bhn = biasf[5632 + j];
#pragma unroll
        for (int r = 0; r < 4; r++) {
            int m = mw + quad * 4 + r;
            float hp = h1f ? h1f[(size_t)m * MEM + j] : b2f(h1b[(size_t)m * MEM + j]);
            float rr = sigm(acc[0][r] + bir + bhr);
            float zz = sigm(acc[1][r] + biz + bhz);
            float nn = tanh_f(acc[2][r] + bin + rr * (acc[3][r] + bhn));
            float h = (1.0f - zz) * nn + zz * hp;
            outb[(size_t)m * MEM + j] = f2b(h);
            if (outf) outf[(size_t)m * MEM + j] = h;
        }
    } else {
        float gir = biasf[6144 + j], giz = biasf[6656 + j], gin = biasf[7168 + j];
        float bhr = biasf[7680 + j], bhz = biasf[8192 + j], bhn = biasf[8704 + j];
#pragma unroll
        for (int r = 0; r < 4; r++) {
            int m = mw + quad * 4 + r;
            float hp = h2f ? h2f[(size_t)m * MEM + j] : b2f(h2b[(size_t)m * MEM + j]);
            float rr = sigm(gir + acc[0][r] + bhr);
            float zz = sigm(giz + acc[1][r] + bhz);
            float nn = tanh_f(gin + rr * (acc[2][r] + bhn));
            float h = (1.0f - zz) * nn + zz * hp;
            outb[(size_t)m * MEM + j] = f2b(h);
        }
    }
}

// ================= SMALL-LEVEL KERNELS (r3-proven, levels n<=64) =================

__launch_bounds__(256)
__global__ void gemm_stage1(const unsigned short* __restrict__ states,
                            const unsigned short* __restrict__ T2,
                            const unsigned short* __restrict__ Wi,
                            const float* __restrict__ biasf,
                            int n,
                            unsigned short* __restrict__ h1b,
                            float* __restrict__ h1f) {
    int wv = threadIdx.x >> 6, lane = threadIdx.x & 63;
    int l15 = lane & 15, quad = lane >> 4, koff = quad * 8;
    int m_blk = blockIdx.x * 64;
    int jb = blockIdx.y * 64 + wv * 16;

    floatx4 acc[4][3];
#pragma unroll
    for (int s = 0; s < 4; s++)
#pragma unroll
        for (int g = 0; g < 3; g++) acc[s][g] = (floatx4){0.f, 0.f, 0.f, 0.f};
    short8 z8 = {0, 0, 0, 0, 0, 0, 0, 0};

    for (int kb = 0; kb < KP_CH; kb += 32) {
        int k0 = kb + koff;
        short8 a[4];
#pragma unroll
        for (int s = 0; s < 4; s++) {
            int row = m_blk + s * 16 + l15;
            if (row >= n) a[s] = z8;
            else if (kb < 512)
                a[s] = *(const short8*)(states + (size_t)(2 * n - 1 + 2 * row) * MEM + k0);
            else
                a[s] = *(const short8*)(T2 + (size_t)row * T2W + (k0 - 512));
        }
        short8 b[3];
#pragma unroll
        for (int g = 0; g < 3; g++)
            b[g] = *(const short8*)(Wi + (size_t)(jb + l15 + g * 512) * KP_CH + k0);
#pragma unroll
        for (int s = 0; s < 4; s++)
#pragma unroll
            for (int g = 0; g < 3; g++)
                acc[s][g] = __builtin_amdgcn_mfma_f32_16x16x32_bf16(a[s], b[g], acc[s][g], 0, 0, 0);
    }

    int j = jb + l15;
    float bir = biasf[3072 + j], biz = biasf[3584 + j], bin = biasf[4096 + j];
    float bhr = biasf[4608 + j], bhz = biasf[5120 + j], bhn = biasf[5632 + j];
#pragma unroll
    for (int s = 0; s < 4; s++)
#pragma unroll
        for (int r = 0; r < 4; r++) {
            int m = m_blk + s * 16 + quad * 4 + r;
            if (m >= n) continue;
            float rr = sigm(acc[s][0][r] + bir + bhr);
            float zz = sigm(acc[s][1][r] + biz + bhz);
            float nn = tanh_f(acc[s][2][r] + bin + rr * bhn);
            float h = (1.0f - zz) * nn;
            h1b[(size_t)m * MEM + j] = f2b(h);
            if (h1f) h1f[(size_t)m * MEM + j] = h;
        }
}

__launch_bounds__(256)
__global__ void gemm_stage2(const unsigned short* __restrict__ states,
                            const unsigned short* __restrict__ T2,
                            const unsigned short* __restrict__ Wi,
                            const unsigned short* __restrict__ h1b,
                            const float* __restrict__ h1f,
                            const unsigned short* __restrict__ Wh,
                            const float* __restrict__ biasf,
                            int n,
                            unsigned short* __restrict__ h2b,
                            float* __restrict__ h2f) {
    int wv = threadIdx.x >> 6, lane = threadIdx.x & 63;
    int l15 = lane & 15, quad = lane >> 4, koff = quad * 8;
    int m_blk = blockIdx.x * 64;
    int jb = blockIdx.y * 64 + wv * 16;

    floatx4 gi[4][3], gh[4][3];
#pragma unroll
    for (int s = 0; s < 4; s++)
#pragma unroll
        for (int g = 0; g < 3; g++) {
            gi[s][g] = (floatx4){0.f, 0.f, 0.f, 0.f};
            gh[s][g] = (floatx4){0.f, 0.f, 0.f, 0.f};
        }
    short8 z8 = {0, 0, 0, 0, 0, 0, 0, 0};

    for (int kb = 0; kb < KP_CH; kb += 32) {
        int k0 = kb + koff;
        short8 a[4];
#pragma unroll
        for (int s = 0; s < 4; s++) {
            int row = m_blk + s * 16 + l15;
            if (row >= n) a[s] = z8;
            else if (kb < 512)
                a[s] = *(const short8*)(states + (size_t)(2 * n + 2 * row) * MEM + k0);
            else
                a[s] = *(const short8*)(T2 + (size_t)(n + row) * T2W + (k0 - 512));
        }
        short8 b[3];
#pragma unroll
        for (int g = 0; g < 3; g++)
            b[g] = *(const short8*)(Wi + (size_t)(jb + l15 + g * 512) * KP_CH + k0);
#pragma unroll
        for (int s = 0; s < 4; s++)
#pragma unroll
            for (int g = 0; g < 3; g++)
                gi[s][g] = __builtin_amdgcn_mfma_f32_16x16x32_bf16(a[s], b[g], gi[s][g], 0, 0, 0);
    }

    for (int kb = 0; kb < MEM; kb += 32) {
        int k0 = kb + koff;
        short8 a[4];
#pragma unroll
        for (int s = 0; s < 4; s++) {
            int row = m_blk + s * 16 + l15;
            a[s] = (row < n) ? *(const short8*)(h1b + (size_t)row * MEM + k0) : z8;
        }
        short8 b[3];
#pragma unroll
        for (int g = 0; g < 3; g++)
            b[g] = *(const short8*)(Wh + (size_t)(jb + l15 + g * 512) * MEM + k0);
#pragma unroll
        for (int s = 0; s < 4; s++)
#pragma unroll
            for (int g = 0; g < 3; g++)
                gh[s][g] = __builtin_amdgcn_mfma_f32_16x16x32_bf16(a[s], b[g], gh[s][g], 0, 0, 0);
    }

    int j = jb + l15;
    float bir = biasf[3072 + j], biz = biasf[3584 + j], bin = biasf[4096 + j];
    float bhr = biasf[4608 + j], bhz = biasf[5120 + j], bhn = biasf[5632 + j];
#pragma unroll
    for (int s = 0; s < 4; s++)
#pragma unroll
        for (int r = 0; r < 4; r++) {
            int m = m_blk + s * 16 + quad * 4 + r;
            if (m >= n) continue;
            float hp = h1f ? h1f[(size_t)m * MEM + j] : b2f(h1b[(size_t)m * MEM + j]);
            float rr = sigm(gi[s][0][r] + bir + gh[s][0][r] + bhr);
            float zz = sigm(gi[s][1][r] + biz + gh[s][1][r] + bhz);
            float nn = tanh_f(gi[s][2][r] + bin + rr * (gh[s][2][r] + bhn));
            float h = (1.0f - zz) * nn + zz * hp;
            h2b[(size_t)m * MEM + j] = f2b(h);
            if (h2f) h2f[(size_t)m * MEM + j] = h;
        }
}

__launch_bounds__(256)
__global__ void gemm_stage3(const unsigned short* __restrict__ h2b,
                            const float* __restrict__ h2f,
                            const unsigned short* __restrict__ Wh,
                            const float* __restrict__ biasf,
                            int n,
                            unsigned short* __restrict__ out,
                            float* __restrict__ outf) {
    int wv = threadIdx.x >> 6, lane = threadIdx.x & 63;
    int l15 = lane & 15, quad = lane >> 4, koff = quad * 8;
    int m_blk = blockIdx.x * 64;
    int jb = blockIdx.y * 64 + wv * 16;

    floatx4 acc[4][3];
#pragma unroll
    for (int s = 0; s < 4; s++)
#pragma unroll
        for (int g = 0; g < 3; g++) acc[s][g] = (floatx4){0.f, 0.f, 0.f, 0.f};
    short8 z8 = {0, 0, 0, 0, 0, 0, 0, 0};

    for (int kb = 0; kb < MEM; kb += 32) {
        int k0 = kb + koff;
        short8 a[4];
#pragma unroll
        for (int s = 0; s < 4; s++) {
            int row = m_blk + s * 16 + l15;
            a[s] = (row < n) ? *(const short8*)(h2b + (size_t)row * MEM + k0) : z8;
        }
        short8 b[3];
#pragma unroll
        for (int g = 0; g < 3; g++)
            b[g] = *(const short8*)(Wh + (size_t)(jb + l15 + g * 512) * MEM + k0);
#pragma unroll
        for (int s = 0; s < 4; s++)
#pragma unroll
            for (int g = 0; g < 3; g++)
                acc[s][g] = __builtin_amdgcn_mfma_f32_16x16x32_bf16(a[s], b[g], acc[s][g], 0, 0, 0);
    }

    int j = jb + l15;
    float gir = biasf[6144 + j], giz = biasf[6656 + j], gin = biasf[7168 + j];
    float bhr = biasf[7680 + j], bhz = biasf[8192 + j], bhn = biasf[8704 + j];
#pragma unroll
    for (int s = 0; s < 4; s++)
#pragma unroll
        for (int r = 0; r < 4; r++) {
            int m = m_blk + s * 16 + quad * 4 + r;
            if (m >= n) continue;
            float hp = h2f ? h2f[(size_t)m * MEM + j] : b2f(h2b[(size_t)m * MEM + j]);
            float rr = sigm(gir + acc[s][0][r] + bhr);
            float zz = sigm(giz + acc[s][1][r] + bhz);
            float nn = tanh_f(gin + rr * (acc[s][2][r] + bhn));
            float h = (1.0f - zz) * nn + zz * hp;
            out[(size_t)m * MEM + j] = f2b(h);
            if (outf) outf[(size_t)m * MEM + j] = h;
        }
}

__global__ void copy_out_kernel(const int* __restrict__ flag,
                                const unsigned short* __restrict__ states,
                                const float* __restrict__ rootf,
                                void* __restrict__ out) {
    int j = threadIdx.x;
    if (j >= MEM) return;
    if (*flag) ((float*)out)[j] = rootf[j];
    else ((unsigned short*)out)[j] = states[j];
}

// ---------------- launch ----------------

extern "C" void kernel_launch(void* const* d_in, const int* in_sizes, int n_in,
                              void* d_out, int out_size, void* d_ws, size_t ws_size,
                              hipStream_t stream) {
    const void* embs    = d_in[0];
    const void* tags    = d_in[1];
    const void* leaf_Wi = d_in[2];
    const void* leaf_bi = d_in[4];
    const void* leaf_bh = d_in[5];
    const void* node_Wh = d_in[7];
    const void* node_bi = d_in[8];
    const void* node_bh = d_in[9];
    const void* ch_Wi   = d_in[10];
    const void* ch_Wh   = d_in[11];
    const void* ch_bi   = d_in[12];
    const void* ch_bh   = d_in[13];
    (void)in_sizes; (void)n_in; (void)out_size;

    char* ws = (char*)d_ws;
    const size_t o_flag   = 0;
    const size_t o_bias   = 256;
    const size_t o_Wl     = o_bias + 36864;
    const size_t o_Wc     = o_Wl + (size_t)1536 * KP_LEAF * 2;
    const size_t o_Whc    = o_Wc + (size_t)1536 * KP_CH * 2;
    const size_t o_Whn    = o_Whc + (size_t)1536 * MEM * 2;
    const size_t o_states = o_Whn + (size_t)1536 * MEM * 2;
    const size_t o_T2     = o_states + (size_t)32768 * MEM * 2;
    const size_t o_h1b    = o_T2 + (size_t)32768 * T2W * 2;
    const size_t o_h2b    = o_h1b + (size_t)8192 * MEM * 2;
    const size_t o_rootf  = o_h2b + (size_t)8192 * MEM * 2;
    const size_t o_h1f    = o_rootf + 2048;
    const size_t o_h2f    = o_h1f + (size_t)8192 * MEM * 4;
    const size_t NEED0    = o_h2f + (size_t)8192 * MEM * 4;   // ~105 MB

    bool tier0 = (ws_size >= NEED0);

    int*            flag   = (int*)(ws + o_flag);
    float*          biasf  = (float*)(ws + o_bias);
    unsigned short* Wl     = (unsigned short*)(ws + o_Wl);
    unsigned short* Wc     = (unsigned short*)(ws + o_Wc);
    unsigned short* Whc    = (unsigned short*)(ws + o_Whc);
    unsigned short* Whn    = (unsigned short*)(ws + o_Whn);
    unsigned short* states = (unsigned short*)(ws + o_states);
    unsigned short* T2all  = (unsigned short*)(ws + o_T2);
    unsigned short* h1b    = (unsigned short*)(ws + o_h1b);
    unsigned short* h2b    = (unsigned short*)(ws + o_h2b);
    float*          rootf  = (float*)(ws + o_rootf);
    float*          h1f    = tier0 ? (float*)(ws + o_h1f) : nullptr;
    float*          h2f    = tier0 ? (float*)(ws + o_h2f) : nullptr;
    // Xleaf overlays h1b+h2b (dead before lvl-13 stage1)
    unsigned short* Xleaf  = (unsigned short*)(ws + o_h1b);

    init_kernel<<<1, 64, 0, stream>>>(flag);
    detect_kernel<<<256, 256, 0, stream>>>((const unsigned short*)embs, flag);
    prep_kernel<<<2048, 256, 0, stream>>>(flag, embs, tags,
                                          leaf_Wi, ch_Wi, ch_Wh, node_Wh,
                                          leaf_bi, leaf_bh, ch_bi, ch_bh,
                                          node_bi, node_bh,
                                          Wl, Wc, Whc, Whn, biasf, T2all, Xleaf);

    big3<0><<<(LEAVES / 64) * 8, 256, 0, stream>>>(
        states, T2all, Xleaf, Wl, Wc, Whc, Whn, h1b, h1f, h2b, h2f, biasf,
        LEAVES, states + (size_t)(LEAVES - 1) * MEM, nullptr);

#define LAUNCH_BIG3(M, OB, OF) \
    big3<M><<<(n / 64) * 8, 256, 0, stream>>>( \
        states, T2l, nullptr, Wl, Wc, Whc, Whn, h1b, h1f, h2b, h2f, biasf, n, OB, OF)
#define LAUNCH_BIG2(M, OB, OF) \
    big2<M><<<(n / 64) * 32, 256, 0, stream>>>( \
        states, T2l, Wc, Whc, Whn, h1b, h1f, h2b, h2f, biasf, n, OB, OF)

    for (int lvl = TREE_DEPTH - 1; lvl >= 0; lvl--) {
        int n = 1 << lvl;
        const unsigned short* T2l = T2all + (size_t)(32768 - 4 * n) * T2W;
        unsigned short* st_out = states + (size_t)(n - 1) * MEM;

        if (n >= 2048) {
            LAUNCH_BIG3(1, h1b, h1f);
            LAUNCH_BIG3(2, h2b, h2f);
            LAUNCH_BIG3(3, st_out, nullptr);
        } else if (n >= 128) {
            LAUNCH_BIG2(1, h1b, h1f);
            LAUNCH_BIG2(2, h2b, h2f);
            LAUNCH_BIG2(3, st_out, nullptr);
        } else {
            dim3 g((n + 63) / 64, 8);
            gemm_stage1<<<g, 256, 0, stream>>>(states, T2l, Wc, biasf, n, h1b, h1f);
            gemm_stage2<<<g, 256, 0, stream>>>(states, T2l, Wc, h1b, h1f, Whc, biasf,
                                               n, h2b, h2f);
            gemm_stage3<<<g, 256, 0, stream>>>(h2b, h2f, Whn, biasf, n, st_out,
                                               (n == 1) ? rootf : nullptr);
        }
    }

    copy_out_kernel<<<1, 512, 0, stream>>>(flag, states, rootf, d_out);
}

// Round 12
// 857.534 us; speedup vs baseline: 1.1501x; 1.0828x over previous
//
#include <hip/hip_runtime.h>
#include <stdint.h>

#define MEM 512
#define TAGD 100
#define WORD 300
#define TREE_DEPTH 14
#define LEAVES 16384
#define KLEAF 400
#define KP_LEAF 416
#define KCH 712
#define KP_CH 736
#define T2W 224   // tag_child(100) | tag_parent(100) | pad(24)
#define AP 72     // big3 A-LDS pitch
#define LP 136    // big2 LDS pitch

typedef __attribute__((ext_vector_type(8))) short short8;
typedef __attribute__((ext_vector_type(4))) float floatx4;

__device__ __forceinline__ float b2f(unsigned short u) {
    union { unsigned int i; float f; } v; v.i = ((unsigned int)u) << 16; return v.f;
}
__device__ __forceinline__ unsigned short f2b(float f) {
    union { float f; unsigned int i; } v; v.f = f;
    unsigned int r = v.i + 0x7FFFu + ((v.i >> 16) & 1u);
    return (unsigned short)(r >> 16);
}
__device__ __forceinline__ float sigm(float x) { return 1.0f / (1.0f + __expf(-x)); }
__device__ __forceinline__ float tanh_f(float x) { return 1.0f - 2.0f / (__expf(2.0f * x) + 1.0f); }

// ---------------- init / detect ----------------

__global__ void init_kernel(int* flag) {
    if (blockIdx.x == 0 && threadIdx.x == 0) *flag = 0;
}

__global__ void detect_kernel(const unsigned short* __restrict__ embs_u,
                              int* __restrict__ flag) {
    int tid = blockIdx.x * blockDim.x + threadIdx.x;
    int nth = gridDim.x * blockDim.x;
    int found = 0;
    for (int i = tid; i < 1048576; i += nth) {
        if (((embs_u[i] >> 7) & 0xFF) == 0xFF) { found = 1; break; }
    }
    unsigned long long b = __ballot(found);
    if ((threadIdx.x & 63) == 0 && b != 0ULL) atomicOr(flag, 1);
}

__device__ __forceinline__ unsigned short ld_bf(int f, const void* p, int i) {
    return f ? f2b(((const float*)p)[i]) : ((const unsigned short*)p)[i];
}
__device__ __forceinline__ float ld_f32(int f, const void* p, int i) {
    return f ? ((const float*)p)[i] : b2f(((const unsigned short*)p)[i]);
}

// ---------------- fused prep ----------------

__global__ void prep_kernel(const int* __restrict__ flag,
                            const void* embs, const void* tags,
                            const void* leaf_Wi, const void* ch_Wi,
                            const void* ch_Wh, const void* node_Wh,
                            const void* lbi, const void* lbh,
                            const void* cbi, const void* cbh,
                            const void* nbi, const void* nbh,
                            unsigned short* __restrict__ Wl,
                            unsigned short* __restrict__ Wc,
                            unsigned short* __restrict__ Whc,
                            unsigned short* __restrict__ Whn,
                            float* __restrict__ biasf,
                            unsigned short* __restrict__ T2,
                            unsigned short* __restrict__ X) {
    int f = *flag;
    int tid = blockIdx.x * blockDim.x + threadIdx.x;
    int nth = gridDim.x * blockDim.x;
    for (int idx = tid; idx < 1536 * KP_LEAF; idx += nth) {
        int r = idx / KP_LEAF, c = idx % KP_LEAF;
        Wl[idx] = (c < KLEAF) ? ld_bf(f, leaf_Wi, r * KLEAF + c) : (unsigned short)0;
    }
    for (int idx = tid; idx < 1536 * KP_CH; idx += nth) {
        int r = idx / KP_CH, c = idx % KP_CH;
        Wc[idx] = (c < KCH) ? ld_bf(f, ch_Wi, r * KCH + c) : (unsigned short)0;
    }
    for (int idx = tid; idx < 1536 * MEM; idx += nth) Whc[idx] = ld_bf(f, ch_Wh, idx);
    for (int idx = tid; idx < 1536 * MEM; idx += nth) Whn[idx] = ld_bf(f, node_Wh, idx);
    for (int i = tid; i < 1536; i += nth) {
        biasf[i]            = ld_f32(f, lbi, i);
        biasf[1536 + i]     = ld_f32(f, lbh, i);
        biasf[2 * 1536 + i] = ld_f32(f, cbi, i);
        biasf[3 * 1536 + i] = ld_f32(f, cbh, i);
        biasf[4 * 1536 + i] = ld_f32(f, nbi, i);
        biasf[5 * 1536 + i] = ld_f32(f, nbh, i);
    }
    // T2 all levels: level lvl (n=2^lvl) rows [32768-4n, 32768-4n+2n)
    for (int idx = tid; idx < 32766 * T2W; idx += nth) {
        int r = idx / T2W, c = idx % T2W;
        int d = 32768 - r;
        int lvl = 30 - __clz(d - 1);
        int n = 1 << lvl;
        int i = r - (32768 - 4 * n);
        int half = (i >= n) ? 1 : 0;
        int ii = half ? (i - n) : i;
        int p = (n - 1) + ii;
        int child = 2 * p + 1 + half;
        unsigned short v;
        if (c < TAGD) v = ld_bf(f, tags, child * TAGD + c);
        else if (c < 2 * TAGD) v = ld_bf(f, tags, p * TAGD + (c - TAGD));
        else v = 0;
        T2[idx] = v;
    }
    for (int idx = tid; idx < LEAVES * KP_LEAF; idx += nth) {
        int i = idx / KP_LEAF, c = idx % KP_LEAF;
        unsigned short v;
        if (c < WORD) v = ld_bf(f, embs, i * WORD + c);
        else if (c < WORD + TAGD) v = ld_bf(f, tags, (LEAVES - 1 + i) * TAGD + (c - WORD));
        else v = 0;
        X[idx] = v;
    }
}

struct Chunk {
    const unsigned short* A; int astride; int alpha; int beta;
    const unsigned short* W; int wstride; int wkb; int len;
};

// ================= BIG3 v3 (leaf + levels n>=2048), software-pipelined ==========
// 256 thr / 4 j-waves; tile 64m x 64j x 3 gates; wave = 64m x 16j.
// A(c+1) register-prefetched one chunk ahead; ds_write AFTER compute(c) so its
// vmcnt wait is for chunk-old loads; W(c+1) fragments register-prefetched.
// Supergroup swizzle keeps the 8 j-readers of one m-slice adjacent + same XCD.

template<int MODE>
__launch_bounds__(256, 3)
__global__ void big3(const unsigned short* __restrict__ states,
                     const unsigned short* __restrict__ T2l,
                     const unsigned short* __restrict__ Xleaf,
                     const unsigned short* __restrict__ Wl,
                     const unsigned short* __restrict__ Wc,
                     const unsigned short* __restrict__ Whc,
                     const unsigned short* __restrict__ Whn,
                     const unsigned short* __restrict__ h1b,
                     const float* __restrict__ h1f,
                     const unsigned short* __restrict__ h2b,
                     const float* __restrict__ h2f,
                     const float* __restrict__ biasf,
                     int n,
                     unsigned short* __restrict__ outb,
                     float* __restrict__ outf) {
    constexpr int NCH = (MODE == 0) ? 7 : (MODE == 1) ? 12 : (MODE == 2) ? 20 : 8;
    constexpr int NS  = (MODE == 2) ? 4 : 3;

    int tid = threadIdx.x;
    int w = tid >> 6, lane = tid & 63, l15 = lane & 15, quad = lane >> 4;
    int bid = blockIdx.x;
    int sg = bid >> 6;
    int mb = sg * 8 + (bid & 7);
    int jblk = (bid >> 3) & 7;
    int m_blk = mb * 64;
    int jb = jblk * 64;

    __shared__ unsigned short lA[2][64 * AP];

    const unsigned short* T2r = T2l + (size_t)n * T2W;

    auto getch = [&](int c) -> Chunk {
        if (MODE == 0) {
            return Chunk{Xleaf + c * 64, KP_LEAF, 1, 0, Wl, KP_LEAF, c * 64, (c < 6) ? 64 : 32};
        } else if (MODE == 1) {
            if (c < 8) return Chunk{states + c * 64, MEM, 2, 2 * n - 1, Wc, KP_CH, c * 64, 64};
            int kb = (c - 8) * 64;
            return Chunk{T2l + kb, T2W, 1, 0, Wc, KP_CH, 512 + kb, (c < 11) ? 64 : 32};
        } else if (MODE == 2) {
            if (c < 8) return Chunk{states + c * 64, MEM, 2, 2 * n, Wc, KP_CH, c * 64, 64};
            if (c < 12) {
                int kb = (c - 8) * 64;
                return Chunk{T2r + kb, T2W, 1, 0, Wc, KP_CH, 512 + kb, (c < 11) ? 64 : 32};
            }
            int kb = (c - 12) * 64;
            return Chunk{h1b + kb, MEM, 1, 0, Whc, MEM, kb, 64};
        } else {
            return Chunk{h2b + c * 64, MEM, 1, 0, Whn, MEM, c * 64, 64};
        }
    };

    auto loadA = [&](Chunk k, short8* ar) {
        if (k.len == 64) {
#pragma unroll
            for (int p = 0; p < 2; p++) {
                int idx = tid + p * 256;
                int row = idx >> 3, gr = idx & 7;
                ar[p] = *(const short8*)(k.A +
                    (size_t)(k.alpha * (m_blk + row) + k.beta) * k.astride + gr * 8);
            }
        } else {
            int row = tid >> 2, gr = tid & 3;
            ar[0] = *(const short8*)(k.A +
                (size_t)(k.alpha * (m_blk + row) + k.beta) * k.astride + gr * 8);
        }
    };
    auto writeA = [&](int len, const short8* ar, int buf) {
        if (len == 64) {
#pragma unroll
            for (int p = 0; p < 2; p++) {
                int idx = tid + p * 256;
                int row = idx >> 3, gr = idx & 7;
                *(short8*)(&lA[buf][row * AP + gr * 8]) = ar[p];
            }
        } else {
            int row = tid >> 2, gr = tid & 3;
            *(short8*)(&lA[buf][row * AP + gr * 8]) = ar[0];
        }
    };
    auto loadW = [&](Chunk k, short8 (*wr)[3]) {
        int wrow = jb + w * 16 + l15;
#pragma unroll
        for (int ki = 0; ki < 2; ki++) {
            if (ki * 32 < k.len) {
#pragma unroll
                for (int g = 0; g < 3; g++)
                    wr[ki][g] = *(const short8*)(k.W +
                        (size_t)(g * 512 + wrow) * k.wstride + k.wkb + ki * 32 + quad * 8);
            }
        }
    };

    floatx4 acc[4][NS];
#pragma unroll
    for (int s = 0; s < 4; s++)
#pragma unroll
        for (int g = 0; g < NS; g++) acc[s][g] = (floatx4){0.f, 0.f, 0.f, 0.f};

    short8 Aset[2][2];
    short8 Wset[2][2][3];

    {
        Chunk c0 = getch(0);
        loadA(c0, Aset[0]);
        writeA(c0.len, Aset[0], 0);
        if (NCH > 1) loadA(getch(1), Aset[1]);
        loadW(c0, Wset[0]);
    }
    __syncthreads();

#pragma unroll
    for (int c = 0; c < NCH; c++) {
        Chunk k = getch(c);
        if (c + 1 < NCH) loadW(getch(c + 1), Wset[(c + 1) & 1]);
        const unsigned short* la = &lA[c & 1][l15 * AP + quad * 8];
#pragma unroll
        for (int ki = 0; ki < 2; ki++) {
            if (ki * 32 < k.len) {
                short8 a[4];
#pragma unroll
                for (int s = 0; s < 4; s++)
                    a[s] = *(const short8*)(la + s * 16 * AP + ki * 32);
#pragma unroll
                for (int s = 0; s < 4; s++)
                    acc[s][0] = __builtin_amdgcn_mfma_f32_16x16x32_bf16(a[s], Wset[c & 1][ki][0], acc[s][0], 0, 0, 0);
#pragma unroll
                for (int s = 0; s < 4; s++)
                    acc[s][1] = __builtin_amdgcn_mfma_f32_16x16x32_bf16(a[s], Wset[c & 1][ki][1], acc[s][1], 0, 0, 0);
                if (MODE == 2 && c >= 12) {
#pragma unroll
                    for (int s = 0; s < 4; s++)
                        acc[s][3] = __builtin_amdgcn_mfma_f32_16x16x32_bf16(a[s], Wset[c & 1][ki][2], acc[s][3], 0, 0, 0);
                } else {
#pragma unroll
                    for (int s = 0; s < 4; s++)
                        acc[s][2] = __builtin_amdgcn_mfma_f32_16x16x32_bf16(a[s], Wset[c & 1][ki][2], acc[s][2], 0, 0, 0);
                }
            }
        }
        if (c + 1 < NCH) {
            if (c + 2 < NCH) loadA(getch(c + 2), Aset[c & 1]);
            writeA(getch(c + 1).len, Aset[(c + 1) & 1], (c + 1) & 1);
            __syncthreads();
        }
    }

    int j = jb + w * 16 + l15;
    if (MODE == 0 || MODE == 1) {
        int bo = (MODE == 0) ? 0 : 3072;
        float bir = biasf[bo + j], biz = biasf[bo + 512 + j], bin = biasf[bo + 1024 + j];
        float bhr = biasf[bo + 1536 + j], bhz = biasf[bo + 2048 + j], bhn = biasf[bo + 2560 + j];
#pragma unroll
        for (int s = 0; s < 4; s++)
#pragma unroll
            for (int r = 0; r < 4; r++) {
                int m = m_blk + s * 16 + quad * 4 + r;
                float rr = sigm(acc[s][0][r] + bir + bhr);
                float zz = sigm(acc[s][1][r] + biz + bhz);
                float nn = tanh_f(acc[s][2][r] + bin + rr * bhn);
                float h = (1.0f - zz) * nn;
                outb[(size_t)m * MEM + j] = f2b(h);
                if (MODE == 1 && outf) outf[(size_t)m * MEM + j] = h;
            }
    } else if (MODE == 2) {
        float bir = biasf[3072 + j], biz = biasf[3584 + j], bin = biasf[4096 + j];
        float bhr = biasf[4608 + j], bhz = biasf[5120 + j], bhn = biasf[5632 + j];
#pragma unroll
        for (int s = 0; s < 4; s++)
#pragma unroll
            for (int r = 0; r < 4; r++) {
                int m = m_blk + s * 16 + quad * 4 + r;
                float hp = h1f ? h1f[(size_t)m * MEM + j] : b2f(h1b[(size_t)m * MEM + j]);
                float rr = sigm(acc[s][0][r] + bir + bhr);
                float zz = sigm(acc[s][1][r] + biz + bhz);
                float nn = tanh_f(acc[s][2][r] + bin + rr * (acc[s][3][r] + bhn));
                float h = (1.0f - zz) * nn + zz * hp;
                outb[(size_t)m * MEM + j] = f2b(h);
                if (outf) outf[(size_t)m * MEM + j] = h;
            }
    } else {
        float gir = biasf[6144 + j], giz = biasf[6656 + j], gin = biasf[7168 + j];
        float bhr = biasf[7680 + j], bhz = biasf[8192 + j], bhn = biasf[8704 + j];
#pragma unroll
        for (int s = 0; s < 4; s++)
#pragma unroll
            for (int r = 0; r < 4; r++) {
                int m = m_blk + s * 16 + quad * 4 + r;
                float hp = h2f ? h2f[(size_t)m * MEM + j] : b2f(h2b[(size_t)m * MEM + j]);
                float rr = sigm(gir + acc[s][0][r] + bhr);
                float zz = sigm(giz + acc[s][1][r] + bhz);
                float nn = tanh_f(gin + rr * (acc[s][2][r] + bhn));
                float h = (1.0f - zz) * nn + zz * hp;
                outb[(size_t)m * MEM + j] = f2b(h);
            }
    }
}

// ================= BIG2 v2 (mid levels 128..1024), software-pipelined ==========
// W(c+1) register-prefetched, ds_write after compute; A(c+1) register-prefetched.

template<int MODE>
__launch_bounds__(256, 2)
__global__ void big2(const unsigned short* __restrict__ states,
                     const unsigned short* __restrict__ T2l,
                     const unsigned short* __restrict__ Wc,
                     const unsigned short* __restrict__ Whc,
                     const unsigned short* __restrict__ Whn,
                     const unsigned short* __restrict__ h1b,
                     const float* __restrict__ h1f,
                     const unsigned short* __restrict__ h2b,
                     const float* __restrict__ h2f,
                     const float* __restrict__ biasf,
                     int n,
                     unsigned short* __restrict__ outb,
                     float* __restrict__ outf) {
    constexpr int NCH = (MODE == 1) ? 6 : (MODE == 2) ? 10 : 4;
    constexpr int NS  = (MODE == 2) ? 4 : 3;

    int tid = threadIdx.x;
    int w = tid >> 6, lane = tid & 63, l15 = lane & 15, quad = lane >> 4;
    int Nm = n >> 6;
    int bid = blockIdx.x;
    int mb, j16;
    if (Nm >= 8) {
        int sg = bid >> 6;
        int mSupers = Nm >> 3;
        mb  = (sg % mSupers) * 8 + (bid & 7);
        j16 = (sg / mSupers) * 8 + ((bid >> 3) & 7);
    } else {
        mb = bid % Nm; j16 = bid / Nm;
    }
    int m_blk = mb * 64;
    int jb = j16 * 16;
    int mw = m_blk + w * 16;

    __shared__ unsigned short lds[2][48 * LP];

    const unsigned short* T2r = T2l + (size_t)n * T2W;

    auto getch = [&](int c) -> Chunk {
        if (MODE == 1) {
            if (c < 4) return Chunk{states + c * 128, MEM, 2, 2 * n - 1, Wc, KP_CH, c * 128, 128};
            if (c == 4) return Chunk{T2l, T2W, 1, 0, Wc, KP_CH, 512, 128};
            return Chunk{T2l + 128, T2W, 1, 0, Wc, KP_CH, 640, 96};
        } else if (MODE == 2) {
            if (c < 4) return Chunk{states + c * 128, MEM, 2, 2 * n, Wc, KP_CH, c * 128, 128};
            if (c == 4) return Chunk{T2r, T2W, 1, 0, Wc, KP_CH, 512, 128};
            if (c == 5) return Chunk{T2r + 128, T2W, 1, 0, Wc, KP_CH, 640, 96};
            int kb = (c - 6) * 128;
            return Chunk{h1b + kb, MEM, 1, 0, Whc, MEM, kb, 128};
        } else {
            int kb = c * 128;
            return Chunk{h2b + kb, MEM, 1, 0, Whn, MEM, kb, 128};
        }
    };

    auto loadW = [&](Chunk k, short8* wrg) {
        int gr = k.len >> 3;
        int kc = tid & 15;
#pragma unroll
        for (int p = 0; p < 3; p++) {
            int row = (tid >> 4) + p * 16;
            if (kc < gr) {
                int gate = row >> 4, jj = row & 15;
                wrg[p] = *(const short8*)(k.W + (size_t)(gate * 512 + jb + jj) * k.wstride + k.wkb + kc * 8);
            }
        }
    };
    auto writeW = [&](int len, const short8* wrg, int buf) {
        int gr = len >> 3;
        int kc = tid & 15;
#pragma unroll
        for (int p = 0; p < 3; p++) {
            int row = (tid >> 4) + p * 16;
            if (kc < gr)
                *(short8*)(&lds[buf][row * LP + kc * 8]) = wrg[p];
        }
    };
    auto loadA = [&](Chunk k, short8* ar) {
#pragma unroll
        for (int ki = 0; ki < 4; ki++) {
            if (ki * 32 < k.len) {
                ar[ki] = *(const short8*)(k.A +
                    (size_t)(k.alpha * (mw + l15) + k.beta) * k.astride +
                    quad * 8 + ki * 32);
            }
        }
    };

    floatx4 acc[NS];
#pragma unroll
    for (int g = 0; g < NS; g++) acc[g] = (floatx4){0.f, 0.f, 0.f, 0.f};

    short8 Wst[2][3];
    short8 Ast[2][4];

    {
        Chunk c0 = getch(0);
        loadW(c0, Wst[0]);
        writeW(c0.len, Wst[0], 0);
        if (NCH > 1) loadW(getch(1), Wst[1]);
        loadA(c0, Ast[0]);
    }
    __syncthreads();

#pragma unroll
    for (int c = 0; c < NCH; c++) {
        Chunk k = getch(c);
        if (c + 1 < NCH) loadA(getch(c + 1), Ast[(c + 1) & 1]);
        const unsigned short* lb = &lds[c & 1][l15 * LP + quad * 8];
#pragma unroll
        for (int ki = 0; ki < 4; ki++) {
            if (ki * 32 < k.len) {
                short8 b0 = *(const short8*)(lb + ki * 32);
                short8 b1 = *(const short8*)(lb + 16 * LP + ki * 32);
                short8 b2 = *(const short8*)(lb + 32 * LP + ki * 32);
                acc[0] = __builtin_amdgcn_mfma_f32_16x16x32_bf16(Ast[c & 1][ki], b0, acc[0], 0, 0, 0);
                acc[1] = __builtin_amdgcn_mfma_f32_16x16x32_bf16(Ast[c & 1][ki], b1, acc[1], 0, 0, 0);
                if (MODE == 2 && c >= 6)
                    acc[3] = __builtin_amdgcn_mfma_f32_16x16x32_bf16(Ast[c & 1][ki], b2, acc[3], 0, 0, 0);
                else
                    acc[2] = __builtin_amdgcn_mfma_f32_16x16x32_bf16(Ast[c & 1][ki], b2, acc[2], 0, 0, 0);
            }
        }
        if (c + 1 < NCH) {
            if (c + 2 < NCH) loadW(getch(c + 2), Wst[c & 1]);
            writeW(getch(c + 1).len, Wst[(c + 1) & 1], (c + 1) & 1);
            __syncthreads();
        }
    }

    int j = jb + l15;
    if (MODE == 1) {
        float bir = biasf[3072 + j], biz = biasf[3584 + j], bin = biasf[4096 + j];
        float bhr = biasf[4608 + j], bhz = biasf[5120 + j], bhn = biasf[5632 + j];
#pragma unroll
        for (int r = 0; r < 4; r++) {
            int m = mw + quad * 4 + r;
            float rr = sigm(acc[0][r] + bir + bhr);
            float zz = sigm(acc[1][r] + biz + bhz);
            float nn = tanh_f(acc[2][r] + bin + rr * bhn);
            float h = (1.0f - zz) * nn;
            outb[(size_t)m * MEM + j] = f2b(h);
            if (outf) outf[(size_t)m * MEM + j] = h;
        }
    } else if (MODE == 2) {
        float bir = biasf[3072 + j], biz = biasf[3584 + j], bin = biasf[4096 + j];
        float bhr = biasf[4608 + j], bhz = biasf[5120 + j], bhn = biasf[5632 + j];
#pragma unroll
        for (int r = 0; r < 4; r++) {
            int m = mw + quad * 4 + r;
            float hp = h1f ? h1f[(size_t)m * MEM + j] : b2f(h1b[(size_t)m * MEM + j]);
            float rr = sigm(acc[0][r] + bir + bhr);
            float zz = sigm(acc[1][r] + biz + bhz);
            float nn = tanh_f(acc[2][r] + bin + rr * (acc[3][r] + bhn));
            float h = (1.0f - zz) * nn + zz * hp;
            outb[(size_t)m * MEM + j] = f2b(h);
            if (outf) outf[(size_t)m * MEM + j] = h;
        }
    } else {
        float gir = biasf[6144 + j], giz = biasf[6656 + j], gin = biasf[7168 + j];
        float bhr = biasf[7680 + j], bhz = biasf[8192 + j], bhn = biasf[8704 + j];
#pragma unroll
        for (int r = 0; r < 4; r++) {
            int m = mw + quad * 4 + r;
            float hp = h2f ? h2f[(size_t)m * MEM + j] : b2f(h2b[(size_t)m * MEM + j]);
            float rr = sigm(gir + acc[0][r] + bhr);
            float zz = sigm(giz + acc[1][r] + bhz);
            float nn = tanh_f(gin + rr * (acc[2][r] + bhn));
            float h = (1.0f - zz) * nn + zz * hp;
            outb[(size_t)m * MEM + j] = f2b(h);
        }
    }
}

// ================= SMALL-LEVEL KERNELS (r3-proven, levels n<=64) =================

__launch_bounds__(256)
__global__ void gemm_stage1(const unsigned short* __restrict__ states,
                            const unsigned short* __restrict__ T2,
                            const unsigned short* __restrict__ Wi,
                            const float* __restrict__ biasf,
                            int n,
                            unsigned short* __restrict__ h1b,
                            float* __restrict__ h1f) {
    int wv = threadIdx.x >> 6, lane = threadIdx.x & 63;
    int l15 = lane & 15, quad = lane >> 4, koff = quad * 8;
    int m_blk = blockIdx.x * 64;
    int jb = blockIdx.y * 64 + wv * 16;

    floatx4 acc[4][3];
#pragma unroll
    for (int s = 0; s < 4; s++)
#pragma unroll
        for (int g = 0; g < 3; g++) acc[s][g] = (floatx4){0.f, 0.f, 0.f, 0.f};
    short8 z8 = {0, 0, 0, 0, 0, 0, 0, 0};

    for (int kb = 0; kb < KP_CH; kb += 32) {
        int k0 = kb + koff;
        short8 a[4];
#pragma unroll
        for (int s = 0; s < 4; s++) {
            int row = m_blk + s * 16 + l15;
            if (row >= n) a[s] = z8;
            else if (kb < 512)
                a[s] = *(const short8*)(states + (size_t)(2 * n - 1 + 2 * row) * MEM + k0);
            else
                a[s] = *(const short8*)(T2 + (size_t)row * T2W + (k0 - 512));
        }
        short8 b[3];
#pragma unroll
        for (int g = 0; g < 3; g++)
            b[g] = *(const short8*)(Wi + (size_t)(jb + l15 + g * 512) * KP_CH + k0);
#pragma unroll
        for (int s = 0; s < 4; s++)
#pragma unroll
            for (int g = 0; g < 3; g++)
                acc[s][g] = __builtin_amdgcn_mfma_f32_16x16x32_bf16(a[s], b[g], acc[s][g], 0, 0, 0);
    }

    int j = jb + l15;
    float bir = biasf[3072 + j], biz = biasf[3584 + j], bin = biasf[4096 + j];
    float bhr = biasf[4608 + j], bhz = biasf[5120 + j], bhn = biasf[5632 + j];
#pragma unroll
    for (int s = 0; s < 4; s++)
#pragma unroll
        for (int r = 0; r < 4; r++) {
            int m = m_blk + s * 16 + quad * 4 + r;
            if (m >= n) continue;
            float rr = sigm(acc[s][0][r] + bir + bhr);
            float zz = sigm(acc[s][1][r] + biz + bhz);
            float nn = tanh_f(acc[s][2][r] + bin + rr * bhn);
            float h = (1.0f - zz) * nn;
            h1b[(size_t)m * MEM + j] = f2b(h);
            if (h1f) h1f[(size_t)m * MEM + j] = h;
        }
}

__launch_bounds__(256)
__global__ void gemm_stage2(const unsigned short* __restrict__ states,
                            const unsigned short* __restrict__ T2,
                            const unsigned short* __restrict__ Wi,
                            const unsigned short* __restrict__ h1b,
                            const float* __restrict__ h1f,
                            const unsigned short* __restrict__ Wh,
                            const float* __restrict__ biasf,
                            int n,
                            unsigned short* __restrict__ h2b,
                            float* __restrict__ h2f) {
    int wv = threadIdx.x >> 6, lane = threadIdx.x & 63;
    int l15 = lane & 15, quad = lane >> 4, koff = quad * 8;
    int m_blk = blockIdx.x * 64;
    int jb = blockIdx.y * 64 + wv * 16;

    floatx4 gi[4][3], gh[4][3];
#pragma unroll
    for (int s = 0; s < 4; s++)
#pragma unroll
        for (int g = 0; g < 3; g++) {
            gi[s][g] = (floatx4){0.f, 0.f, 0.f, 0.f};
            gh[s][g] = (floatx4){0.f, 0.f, 0.f, 0.f};
        }
    short8 z8 = {0, 0, 0, 0, 0, 0, 0, 0};

    for (int kb = 0; kb < KP_CH; kb += 32) {
        int k0 = kb + koff;
        short8 a[4];
#pragma unroll
        for (int s = 0; s < 4; s++) {
            int row = m_blk + s * 16 + l15;
            if (row >= n) a[s] = z8;
            else if (kb < 512)
                a[s] = *(const short8*)(states + (size_t)(2 * n + 2 * row) * MEM + k0);
            else
                a[s] = *(const short8*)(T2 + (size_t)(n + row) * T2W + (k0 - 512));
        }
        short8 b[3];
#pragma unroll
        for (int g = 0; g < 3; g++)
            b[g] = *(const short8*)(Wi + (size_t)(jb + l15 + g * 512) * KP_CH + k0);
#pragma unroll
        for (int s = 0; s < 4; s++)
#pragma unroll
            for (int g = 0; g < 3; g++)
                gi[s][g] = __builtin_amdgcn_mfma_f32_16x16x32_bf16(a[s], b[g], gi[s][g], 0, 0, 0);
    }

    for (int kb = 0; kb < MEM; kb += 32) {
        int k0 = kb + koff;
        short8 a[4];
#pragma unroll
        for (int s = 0; s < 4; s++) {
            int row = m_blk + s * 16 + l15;
            a[s] = (row < n) ? *(const short8*)(h1b + (size_t)row * MEM + k0) : z8;
        }
        short8 b[3];
#pragma unroll
        for (int g = 0; g < 3; g++)
            b[g] = *(const short8*)(Wh + (size_t)(jb + l15 + g * 512) * MEM + k0);
#pragma unroll
        for (int s = 0; s < 4; s++)
#pragma unroll
            for (int g = 0; g < 3; g++)
                gh[s][g] = __builtin_amdgcn_mfma_f32_16x16x32_bf16(a[s], b[g], gh[s][g], 0, 0, 0);
    }

    int j = jb + l15;
    float bir = biasf[3072 + j], biz = biasf[3584 + j], bin = biasf[4096 + j];
    float bhr = biasf[4608 + j], bhz = biasf[5120 + j], bhn = biasf[5632 + j];
#pragma unroll
    for (int s = 0; s < 4; s++)
#pragma unroll
        for (int r = 0; r < 4; r++) {
            int m = m_blk + s * 16 + quad * 4 + r;
            if (m >= n) continue;
            float hp = h1f ? h1f[(size_t)m * MEM + j] : b2f(h1b[(size_t)m * MEM + j]);
            float rr = sigm(gi[s][0][r] + bir + gh[s][0][r] + bhr);
            float zz = sigm(gi[s][1][r] + biz + gh[s][1][r] + bhz);
            float nn = tanh_f(gi[s][2][r] + bin + rr * (gh[s][2][r] + bhn));
            float h = (1.0f - zz) * nn + zz * hp;
            h2b[(size_t)m * MEM + j] = f2b(h);
            if (h2f) h2f[(size_t)m * MEM + j] = h;
        }
}

__launch_bounds__(256)
__global__ void gemm_stage3(const unsigned short* __restrict__ h2b,
                            const float* __restrict__ h2f,
                            const unsigned short* __restrict__ Wh,
                            const float* __restrict__ biasf,
                            int n,
                            unsigned short* __restrict__ out,
                            float* __restrict__ outf) {
    int wv = threadIdx.x >> 6, lane = threadIdx.x & 63;
    int l15 = lane & 15, quad = lane >> 4, koff = quad * 8;
    int m_blk = blockIdx.x * 64;
    int jb = blockIdx.y * 64 + wv * 16;

    floatx4 acc[4][3];
#pragma unroll
    for (int s = 0; s < 4; s++)
#pragma unroll
        for (int g = 0; g < 3; g++) acc[s][g] = (floatx4){0.f, 0.f, 0.f, 0.f};
    short8 z8 = {0, 0, 0, 0, 0, 0, 0, 0};

    for (int kb = 0; kb < MEM; kb += 32) {
        int k0 = kb + koff;
        short8 a[4];
#pragma unroll
        for (int s = 0; s < 4; s++) {
            int row = m_blk + s * 16 + l15;
            a[s] = (row < n) ? *(const short8*)(h2b + (size_t)row * MEM + k0) : z8;
        }
        short8 b[3];
#pragma unroll
        for (int g = 0; g < 3; g++)
            b[g] = *(const short8*)(Wh + (size_t)(jb + l15 + g * 512) * MEM + k0);
#pragma unroll
        for (int s = 0; s < 4; s++)
#pragma unroll
            for (int g = 0; g < 3; g++)
                acc[s][g] = __builtin_amdgcn_mfma_f32_16x16x32_bf16(a[s], b[g], acc[s][g], 0, 0, 0);
    }

    int j = jb + l15;
    float gir = biasf[6144 + j], giz = biasf[6656 + j], gin = biasf[7168 + j];
    float bhr = biasf[7680 + j], bhz = biasf[8192 + j], bhn = biasf[8704 + j];
#pragma unroll
    for (int s = 0; s < 4; s++)
#pragma unroll
        for (int r = 0; r < 4; r++) {
            int m = m_blk + s * 16 + quad * 4 + r;
            if (m >= n) continue;
            float hp = h2f ? h2f[(size_t)m * MEM + j] : b2f(h2b[(size_t)m * MEM + j]);
            float rr = sigm(gir + acc[s][0][r] + bhr);
            float zz = sigm(giz + acc[s][1][r] + bhz);
            float nn = tanh_f(gin + rr * (acc[s][2][r] + bhn));
            float h = (1.0f - zz) * nn + zz * hp;
            out[(size_t)m * MEM + j] = f2b(h);
            if (outf) outf[(size_t)m * MEM + j] = h;
        }
}

__global__ void copy_out_kernel(const int* __restrict__ flag,
                                const unsigned short* __restrict__ states,
                                const float* __restrict__ rootf,
                                void* __restrict__ out) {
    int j = threadIdx.x;
    if (j >= MEM) return;
    if (*flag) ((float*)out)[j] = rootf[j];
    else ((unsigned short*)out)[j] = states[j];
}

// ---------------- launch ----------------

extern "C" void kernel_launch(void* const* d_in, const int* in_sizes, int n_in,
                              void* d_out, int out_size, void* d_ws, size_t ws_size,
                              hipStream_t stream) {
    const void* embs    = d_in[0];
    const void* tags    = d_in[1];
    const void* leaf_Wi = d_in[2];
    const void* leaf_bi = d_in[4];
    const void* leaf_bh = d_in[5];
    const void* node_Wh = d_in[7];
    const void* node_bi = d_in[8];
    const void* node_bh = d_in[9];
    const void* ch_Wi   = d_in[10];
    const void* ch_Wh   = d_in[11];
    const void* ch_bi   = d_in[12];
    const void* ch_bh   = d_in[13];
    (void)in_sizes; (void)n_in; (void)out_size;

    char* ws = (char*)d_ws;
    const size_t o_flag   = 0;
    const size_t o_bias   = 256;
    const size_t o_Wl     = o_bias + 36864;
    const size_t o_Wc     = o_Wl + (size_t)1536 * KP_LEAF * 2;
    const size_t o_Whc    = o_Wc + (size_t)1536 * KP_CH * 2;
    const size_t o_Whn    = o_Whc + (size_t)1536 * MEM * 2;
    const size_t o_states = o_Whn + (size_t)1536 * MEM * 2;
    const size_t o_T2     = o_states + (size_t)32768 * MEM * 2;
    const size_t o_h1b    = o_T2 + (size_t)32768 * T2W * 2;
    const size_t o_h2b    = o_h1b + (size_t)8192 * MEM * 2;
    const size_t o_rootf  = o_h2b + (size_t)8192 * MEM * 2;
    const size_t o_h1f    = o_rootf + 2048;
    const size_t o_h2f    = o_h1f + (size_t)8192 * MEM * 4;
    const size_t NEED0    = o_h2f + (size_t)8192 * MEM * 4;   // ~105 MB

    bool tier0 = (ws_size >= NEED0);

    int*            flag   = (int*)(ws + o_flag);
    float*          biasf  = (float*)(ws + o_bias);
    unsigned short* Wl     = (unsigned short*)(ws + o_Wl);
    unsigned short* Wc     = (unsigned short*)(ws + o_Wc);
    unsigned short* Whc    = (unsigned short*)(ws + o_Whc);
    unsigned short* Whn    = (unsigned short*)(ws + o_Whn);
    unsigned short* states = (unsigned short*)(ws + o_states);
    unsigned short* T2all  = (unsigned short*)(ws + o_T2);
    unsigned short* h1b    = (unsigned short*)(ws + o_h1b);
    unsigned short* h2b    = (unsigned short*)(ws + o_h2b);
    float*          rootf  = (float*)(ws + o_rootf);
    float*          h1f    = tier0 ? (float*)(ws + o_h1f) : nullptr;
    float*          h2f    = tier0 ? (float*)(ws + o_h2f) : nullptr;
    // Xleaf overlays h1b+h2b (dead before lvl-13 stage1)
    unsigned short* Xleaf  = (unsigned short*)(ws + o_h1b);

    init_kernel<<<1, 64, 0, stream>>>(flag);
    detect_kernel<<<256, 256, 0, stream>>>((const unsigned short*)embs, flag);
    prep_kernel<<<2048, 256, 0, stream>>>(flag, embs, tags,
                                          leaf_Wi, ch_Wi, ch_Wh, node_Wh,
                                          leaf_bi, leaf_bh, ch_bi, ch_bh,
                                          node_bi, node_bh,
                                          Wl, Wc, Whc, Whn, biasf, T2all, Xleaf);

    big3<0><<<(LEAVES / 64) * 8, 256, 0, stream>>>(
        states, T2all, Xleaf, Wl, Wc, Whc, Whn, h1b, h1f, h2b, h2f, biasf,
        LEAVES, states + (size_t)(LEAVES - 1) * MEM, nullptr);

#define LAUNCH_BIG3(M, OB, OF) \
    big3<M><<<(n / 64) * 8, 256, 0, stream>>>( \
        states, T2l, nullptr, Wl, Wc, Whc, Whn, h1b, h1f, h2b, h2f, biasf, n, OB, OF)
#define LAUNCH_BIG2(M, OB, OF) \
    big2<M><<<(n / 64) * 32, 256, 0, stream>>>( \
        states, T2l, Wc, Whc, Whn, h1b, h1f, h2b, h2f, biasf, n, OB, OF)

    for (int lvl = TREE_DEPTH - 1; lvl >= 0; lvl--) {
        int n = 1 << lvl;
        const unsigned short* T2l = T2all + (size_t)(32768 - 4 * n) * T2W;
        unsigned short* st_out = states + (size_t)(n - 1) * MEM;

        if (n >= 2048) {
            LAUNCH_BIG3(1, h1b, h1f);
            LAUNCH_BIG3(2, h2b, h2f);
            LAUNCH_BIG3(3, st_out, nullptr);
        } else if (n >= 128) {
            LAUNCH_BIG2(1, h1b, h1f);
            LAUNCH_BIG2(2, h2b, h2f);
            LAUNCH_BIG2(3, st_out, nullptr);
        } else {
            dim3 g((n + 63) / 64, 8);
            gemm_stage1<<<g, 256, 0, stream>>>(states, T2l, Wc, biasf, n, h1b, h1f);
            gemm_stage2<<<g, 256, 0, stream>>>(states, T2l, Wc, h1b, h1f, Whc, biasf,
                                               n, h2b, h2f);
            gemm_stage3<<<g, 256, 0, stream>>>(h2b, h2f, Whn, biasf, n, st_out,
                                               (n == 1) ? rootf : nullptr);
        }
    }

    copy_out_kernel<<<1, 512, 0, stream>>>(flag, states, rootf, d_out);
}

// Round 13
// 608.541 us; speedup vs baseline: 1.6207x; 1.4092x over previous
//
#include <hip/hip_runtime.h>
#include <stdint.h>

#define MEM 512
#define TAGD 100
#define WORD 300
#define TREE_DEPTH 14
#define LEAVES 16384
#define KLEAF 400
#define KP_LEAF 416
#define KCH 712
#define KP_CH 736
#define T2W 224   // tag_child(100) | tag_parent(100) | pad(24)
#define AP 72     // big3 A-LDS pitch
#define LP 136    // mid LDS pitch

typedef __attribute__((ext_vector_type(8))) short short8;
typedef __attribute__((ext_vector_type(4))) float floatx4;

__device__ __forceinline__ float b2f(unsigned short u) {
    union { unsigned int i; float f; } v; v.i = ((unsigned int)u) << 16; return v.f;
}
__device__ __forceinline__ unsigned short f2b(float f) {
    union { float f; unsigned int i; } v; v.f = f;
    unsigned int r = v.i + 0x7FFFu + ((v.i >> 16) & 1u);
    return (unsigned short)(r >> 16);
}
__device__ __forceinline__ float sigm(float x) { return 1.0f / (1.0f + __expf(-x)); }
__device__ __forceinline__ float tanh_f(float x) { return 1.0f - 2.0f / (__expf(2.0f * x) + 1.0f); }

// ---------------- init / detect ----------------

__global__ void init_kernel(int* flag) {
    if (blockIdx.x == 0 && threadIdx.x == 0) *flag = 0;
}

__global__ void detect_kernel(const unsigned short* __restrict__ embs_u,
                              int* __restrict__ flag) {
    int tid = blockIdx.x * blockDim.x + threadIdx.x;
    int nth = gridDim.x * blockDim.x;
    int found = 0;
    for (int i = tid; i < 1048576; i += nth) {
        if (((embs_u[i] >> 7) & 0xFF) == 0xFF) { found = 1; break; }
    }
    unsigned long long b = __ballot(found);
    if ((threadIdx.x & 63) == 0 && b != 0ULL) atomicOr(flag, 1);
}

__device__ __forceinline__ unsigned short ld_bf(int f, const void* p, int i) {
    return f ? f2b(((const float*)p)[i]) : ((const unsigned short*)p)[i];
}
__device__ __forceinline__ float ld_f32(int f, const void* p, int i) {
    return f ? ((const float*)p)[i] : b2f(((const unsigned short*)p)[i]);
}

// ---------------- fused prep ----------------

__global__ void prep_kernel(const int* __restrict__ flag,
                            const void* embs, const void* tags,
                            const void* leaf_Wi, const void* ch_Wi,
                            const void* ch_Wh, const void* node_Wh,
                            const void* lbi, const void* lbh,
                            const void* cbi, const void* cbh,
                            const void* nbi, const void* nbh,
                            unsigned short* __restrict__ Wl,
                            unsigned short* __restrict__ Wc,
                            unsigned short* __restrict__ Whc,
                            unsigned short* __restrict__ Whn,
                            float* __restrict__ biasf,
                            unsigned short* __restrict__ T2,
                            unsigned short* __restrict__ X) {
    int f = *flag;
    int tid = blockIdx.x * blockDim.x + threadIdx.x;
    int nth = gridDim.x * blockDim.x;
    for (int idx = tid; idx < 1536 * KP_LEAF; idx += nth) {
        int r = idx / KP_LEAF, c = idx % KP_LEAF;
        Wl[idx] = (c < KLEAF) ? ld_bf(f, leaf_Wi, r * KLEAF + c) : (unsigned short)0;
    }
    for (int idx = tid; idx < 1536 * KP_CH; idx += nth) {
        int r = idx / KP_CH, c = idx % KP_CH;
        Wc[idx] = (c < KCH) ? ld_bf(f, ch_Wi, r * KCH + c) : (unsigned short)0;
    }
    for (int idx = tid; idx < 1536 * MEM; idx += nth) Whc[idx] = ld_bf(f, ch_Wh, idx);
    for (int idx = tid; idx < 1536 * MEM; idx += nth) Whn[idx] = ld_bf(f, node_Wh, idx);
    for (int i = tid; i < 1536; i += nth) {
        biasf[i]            = ld_f32(f, lbi, i);
        biasf[1536 + i]     = ld_f32(f, lbh, i);
        biasf[2 * 1536 + i] = ld_f32(f, cbi, i);
        biasf[3 * 1536 + i] = ld_f32(f, cbh, i);
        biasf[4 * 1536 + i] = ld_f32(f, nbi, i);
        biasf[5 * 1536 + i] = ld_f32(f, nbh, i);
    }
    // T2 all levels: level lvl (n=2^lvl) rows [32768-4n, 32768-4n+2n)
    for (int idx = tid; idx < 32766 * T2W; idx += nth) {
        int r = idx / T2W, c = idx % T2W;
        int d = 32768 - r;
        int lvl = 30 - __clz(d - 1);
        int n = 1 << lvl;
        int i = r - (32768 - 4 * n);
        int half = (i >= n) ? 1 : 0;
        int ii = half ? (i - n) : i;
        int p = (n - 1) + ii;
        int child = 2 * p + 1 + half;
        unsigned short v;
        if (c < TAGD) v = ld_bf(f, tags, child * TAGD + c);
        else if (c < 2 * TAGD) v = ld_bf(f, tags, p * TAGD + (c - TAGD));
        else v = 0;
        T2[idx] = v;
    }
    for (int idx = tid; idx < LEAVES * KP_LEAF; idx += nth) {
        int i = idx / KP_LEAF, c = idx % KP_LEAF;
        unsigned short v;
        if (c < WORD) v = ld_bf(f, embs, i * WORD + c);
        else if (c < WORD + TAGD) v = ld_bf(f, tags, (LEAVES - 1 + i) * TAGD + (c - WORD));
        else v = 0;
        X[idx] = v;
    }
}

struct Chunk {
    const unsigned short* A; int astride; int alpha; int beta;
    const unsigned short* W; int wstride; int wkb; int len;
};

// ================= BIG3 v3 (leaf + levels n>=2048), software-pipelined ==========

template<int MODE>
__launch_bounds__(256, 3)
__global__ void big3(const unsigned short* __restrict__ states,
                     const unsigned short* __restrict__ T2l,
                     const unsigned short* __restrict__ Xleaf,
                     const unsigned short* __restrict__ Wl,
                     const unsigned short* __restrict__ Wc,
                     const unsigned short* __restrict__ Whc,
                     const unsigned short* __restrict__ Whn,
                     const unsigned short* __restrict__ h1b,
                     const float* __restrict__ h1f,
                     const unsigned short* __restrict__ h2b,
                     const float* __restrict__ h2f,
                     const float* __restrict__ biasf,
                     int n,
                     unsigned short* __restrict__ outb,
                     float* __restrict__ outf) {
    constexpr int NCH = (MODE == 0) ? 7 : (MODE == 1) ? 12 : (MODE == 2) ? 20 : 8;
    constexpr int NS  = (MODE == 2) ? 4 : 3;

    int tid = threadIdx.x;
    int w = tid >> 6, lane = tid & 63, l15 = lane & 15, quad = lane >> 4;
    int bid = blockIdx.x;
    int sg = bid >> 6;
    int mb = sg * 8 + (bid & 7);
    int jblk = (bid >> 3) & 7;
    int m_blk = mb * 64;
    int jb = jblk * 64;

    __shared__ unsigned short lA[2][64 * AP];

    const unsigned short* T2r = T2l + (size_t)n * T2W;

    auto getch = [&](int c) -> Chunk {
        if (MODE == 0) {
            return Chunk{Xleaf + c * 64, KP_LEAF, 1, 0, Wl, KP_LEAF, c * 64, (c < 6) ? 64 : 32};
        } else if (MODE == 1) {
            if (c < 8) return Chunk{states + c * 64, MEM, 2, 2 * n - 1, Wc, KP_CH, c * 64, 64};
            int kb = (c - 8) * 64;
            return Chunk{T2l + kb, T2W, 1, 0, Wc, KP_CH, 512 + kb, (c < 11) ? 64 : 32};
        } else if (MODE == 2) {
            if (c < 8) return Chunk{states + c * 64, MEM, 2, 2 * n, Wc, KP_CH, c * 64, 64};
            if (c < 12) {
                int kb = (c - 8) * 64;
                return Chunk{T2r + kb, T2W, 1, 0, Wc, KP_CH, 512 + kb, (c < 11) ? 64 : 32};
            }
            int kb = (c - 12) * 64;
            return Chunk{h1b + kb, MEM, 1, 0, Whc, MEM, kb, 64};
        } else {
            return Chunk{h2b + c * 64, MEM, 1, 0, Whn, MEM, c * 64, 64};
        }
    };

    auto loadA = [&](Chunk k, short8* ar) {
        if (k.len == 64) {
#pragma unroll
            for (int p = 0; p < 2; p++) {
                int idx = tid + p * 256;
                int row = idx >> 3, gr = idx & 7;
                ar[p] = *(const short8*)(k.A +
                    (size_t)(k.alpha * (m_blk + row) + k.beta) * k.astride + gr * 8);
            }
        } else {
            int row = tid >> 2, gr = tid & 3;
            ar[0] = *(const short8*)(k.A +
                (size_t)(k.alpha * (m_blk + row) + k.beta) * k.astride + gr * 8);
        }
    };
    auto writeA = [&](int len, const short8* ar, int buf) {
        if (len == 64) {
#pragma unroll
            for (int p = 0; p < 2; p++) {
                int idx = tid + p * 256;
                int row = idx >> 3, gr = idx & 7;
                *(short8*)(&lA[buf][row * AP + gr * 8]) = ar[p];
            }
        } else {
            int row = tid >> 2, gr = tid & 3;
            *(short8*)(&lA[buf][row * AP + gr * 8]) = ar[0];
        }
    };
    auto loadW = [&](Chunk k, short8 (*wr)[3]) {
        int wrow = jb + w * 16 + l15;
#pragma unroll
        for (int ki = 0; ki < 2; ki++) {
            if (ki * 32 < k.len) {
#pragma unroll
                for (int g = 0; g < 3; g++)
                    wr[ki][g] = *(const short8*)(k.W +
                        (size_t)(g * 512 + wrow) * k.wstride + k.wkb + ki * 32 + quad * 8);
            }
        }
    };

    floatx4 acc[4][NS];
#pragma unroll
    for (int s = 0; s < 4; s++)
#pragma unroll
        for (int g = 0; g < NS; g++) acc[s][g] = (floatx4){0.f, 0.f, 0.f, 0.f};

    short8 Aset[2][2];
    short8 Wset[2][2][3];

    {
        Chunk c0 = getch(0);
        loadA(c0, Aset[0]);
        writeA(c0.len, Aset[0], 0);
        if (NCH > 1) loadA(getch(1), Aset[1]);
        loadW(c0, Wset[0]);
    }
    __syncthreads();

#pragma unroll
    for (int c = 0; c < NCH; c++) {
        Chunk k = getch(c);
        if (c + 1 < NCH) loadW(getch(c + 1), Wset[(c + 1) & 1]);
        const unsigned short* la = &lA[c & 1][l15 * AP + quad * 8];
#pragma unroll
        for (int ki = 0; ki < 2; ki++) {
            if (ki * 32 < k.len) {
                short8 a[4];
#pragma unroll
                for (int s = 0; s < 4; s++)
                    a[s] = *(const short8*)(la + s * 16 * AP + ki * 32);
#pragma unroll
                for (int s = 0; s < 4; s++)
                    acc[s][0] = __builtin_amdgcn_mfma_f32_16x16x32_bf16(a[s], Wset[c & 1][ki][0], acc[s][0], 0, 0, 0);
#pragma unroll
                for (int s = 0; s < 4; s++)
                    acc[s][1] = __builtin_amdgcn_mfma_f32_16x16x32_bf16(a[s], Wset[c & 1][ki][1], acc[s][1], 0, 0, 0);
                if (MODE == 2 && c >= 12) {
#pragma unroll
                    for (int s = 0; s < 4; s++)
                        acc[s][3] = __builtin_amdgcn_mfma_f32_16x16x32_bf16(a[s], Wset[c & 1][ki][2], acc[s][3], 0, 0, 0);
                } else {
#pragma unroll
                    for (int s = 0; s < 4; s++)
                        acc[s][2] = __builtin_amdgcn_mfma_f32_16x16x32_bf16(a[s], Wset[c & 1][ki][2], acc[s][2], 0, 0, 0);
                }
            }
        }
        if (c + 1 < NCH) {
            if (c + 2 < NCH) loadA(getch(c + 2), Aset[c & 1]);
            writeA(getch(c + 1).len, Aset[(c + 1) & 1], (c + 1) & 1);
            __syncthreads();
        }
    }

    int j = jb + w * 16 + l15;
    if (MODE == 0 || MODE == 1) {
        int bo = (MODE == 0) ? 0 : 3072;
        float bir = biasf[bo + j], biz = biasf[bo + 512 + j], bin = biasf[bo + 1024 + j];
        float bhr = biasf[bo + 1536 + j], bhz = biasf[bo + 2048 + j], bhn = biasf[bo + 2560 + j];
#pragma unroll
        for (int s = 0; s < 4; s++)
#pragma unroll
            for (int r = 0; r < 4; r++) {
                int m = m_blk + s * 16 + quad * 4 + r;
                float rr = sigm(acc[s][0][r] + bir + bhr);
                float zz = sigm(acc[s][1][r] + biz + bhz);
                float nn = tanh_f(acc[s][2][r] + bin + rr * bhn);
                float h = (1.0f - zz) * nn;
                outb[(size_t)m * MEM + j] = f2b(h);
                if (MODE == 1 && outf) outf[(size_t)m * MEM + j] = h;
            }
    } else if (MODE == 2) {
        float bir = biasf[3072 + j], biz = biasf[3584 + j], bin = biasf[4096 + j];
        float bhr = biasf[4608 + j], bhz = biasf[5120 + j], bhn = biasf[5632 + j];
#pragma unroll
        for (int s = 0; s < 4; s++)
#pragma unroll
            for (int r = 0; r < 4; r++) {
                int m = m_blk + s * 16 + quad * 4 + r;
                float hp = h1f ? h1f[(size_t)m * MEM + j] : b2f(h1b[(size_t)m * MEM + j]);
                float rr = sigm(acc[s][0][r] + bir + bhr);
                float zz = sigm(acc[s][1][r] + biz + bhz);
                float nn = tanh_f(acc[s][2][r] + bin + rr * (acc[s][3][r] + bhn));
                float h = (1.0f - zz) * nn + zz * hp;
                outb[(size_t)m * MEM + j] = f2b(h);
                if (outf) outf[(size_t)m * MEM + j] = h;
            }
    } else {
        float gir = biasf[6144 + j], giz = biasf[6656 + j], gin = biasf[7168 + j];
        float bhr = biasf[7680 + j], bhz = biasf[8192 + j], bhn = biasf[8704 + j];
#pragma unroll
        for (int s = 0; s < 4; s++)
#pragma unroll
            for (int r = 0; r < 4; r++) {
                int m = m_blk + s * 16 + quad * 4 + r;
                float hp = h2f ? h2f[(size_t)m * MEM + j] : b2f(h2b[(size_t)m * MEM + j]);
                float rr = sigm(gir + acc[s][0][r] + bhr);
                float zz = sigm(giz + acc[s][1][r] + bhz);
                float nn = tanh_f(gin + rr * (acc[s][2][r] + bhn));
                float h = (1.0f - zz) * nn + zz * hp;
                outb[(size_t)m * MEM + j] = f2b(h);
            }
    }
}

// ================= MID engines (levels n<=1024, one path for all) =================
// midA: M2=2n rows over Wc (K=736). Left rows -> GRU0 -> h1; right rows -> gi+bi (f32).
// midB: gh = h1@Whc (K=512); combine with gi_r -> h2.
// midC: node stage: gh = h2@Whn (K=512); combine -> states (+rootf at lvl0).
// All: pipelined W->LDS dbuf, A register prefetch, row-clamped loads, masked epilogue.

__device__ __forceinline__ void mid_map(int bid, int Nm, int& mb, int& j16) {
    if ((Nm & 7) == 0) {
        int sg = bid >> 6;
        int mSupers = Nm >> 3;
        mb  = (sg % mSupers) * 8 + (bid & 7);
        j16 = (sg / mSupers) * 8 + ((bid >> 3) & 7);
    } else {
        mb = bid % Nm;
        j16 = bid / Nm;
    }
}

__launch_bounds__(256, 2)
__global__ void midA(const unsigned short* __restrict__ states,
                     const unsigned short* __restrict__ T2l,
                     const unsigned short* __restrict__ Wc,
                     const float* __restrict__ biasf,
                     int n,
                     unsigned short* __restrict__ h1b,
                     float* __restrict__ h1f,
                     float* __restrict__ gi_r) {
    constexpr int NCH = 6;
    int tid = threadIdx.x;
    int w = tid >> 6, lane = tid & 63, l15 = lane & 15, quad = lane >> 4;
    int M2 = 2 * n;
    int Nm = (M2 + 63) >> 6;
    int mb, j16;
    mid_map(blockIdx.x, Nm, mb, j16);
    int jb = j16 * 16;
    int mw = mb * 64 + w * 16;

    __shared__ unsigned short lds[2][48 * LP];

    auto wkb = [](int c) { return (c < 4) ? c * 128 : (c == 4) ? 512 : 640; };
    auto clen = [](int c) { return (c == 5) ? 96 : 128; };

    auto loadW = [&](int c, short8* wrg) {
        int gr = clen(c) >> 3;
        int kc = tid & 15;
        int kb = wkb(c);
#pragma unroll
        for (int p = 0; p < 3; p++) {
            int row = (tid >> 4) + p * 16;
            if (kc < gr) {
                int gate = row >> 4, jj = row & 15;
                wrg[p] = *(const short8*)(Wc + (size_t)(gate * 512 + jb + jj) * KP_CH + kb + kc * 8);
            }
        }
    };
    auto writeW = [&](int c, const short8* wrg, int buf) {
        int gr = clen(c) >> 3;
        int kc = tid & 15;
#pragma unroll
        for (int p = 0; p < 3; p++) {
            int row = (tid >> 4) + p * 16;
            if (kc < gr)
                *(short8*)(&lds[buf][row * LP + kc * 8]) = wrg[p];
        }
    };
    auto loadA = [&](int c, short8* ar) {
        int row = mw + l15;
        if (row >= M2) row = M2 - 1;
#pragma unroll
        for (int ki = 0; ki < 4; ki++) {
            if (ki * 32 < clen(c)) {
                if (c < 4) {
                    int half = (row >= n) ? 1 : 0;
                    int i = row - (half ? n : 0);
                    int child = 2 * n - 1 + 2 * i + half;
                    ar[ki] = *(const short8*)(states + (size_t)child * MEM + c * 128 + quad * 8 + ki * 32);
                } else {
                    ar[ki] = *(const short8*)(T2l + (size_t)row * T2W + (wkb(c) - 512) + quad * 8 + ki * 32);
                }
            }
        }
    };

    floatx4 acc[3];
#pragma unroll
    for (int g = 0; g < 3; g++) acc[g] = (floatx4){0.f, 0.f, 0.f, 0.f};

    short8 Wst[2][3];
    short8 Ast[2][4];

    loadW(0, Wst[0]);
    writeW(0, Wst[0], 0);
    loadW(1, Wst[1]);
    loadA(0, Ast[0]);
    __syncthreads();

#pragma unroll
    for (int c = 0; c < NCH; c++) {
        if (c + 1 < NCH) loadA(c + 1, Ast[(c + 1) & 1]);
        const unsigned short* lb = &lds[c & 1][l15 * LP + quad * 8];
#pragma unroll
        for (int ki = 0; ki < 4; ki++) {
            if (ki * 32 < clen(c)) {
                short8 b0 = *(const short8*)(lb + ki * 32);
                short8 b1 = *(const short8*)(lb + 16 * LP + ki * 32);
                short8 b2 = *(const short8*)(lb + 32 * LP + ki * 32);
                acc[0] = __builtin_amdgcn_mfma_f32_16x16x32_bf16(Ast[c & 1][ki], b0, acc[0], 0, 0, 0);
                acc[1] = __builtin_amdgcn_mfma_f32_16x16x32_bf16(Ast[c & 1][ki], b1, acc[1], 0, 0, 0);
                acc[2] = __builtin_amdgcn_mfma_f32_16x16x32_bf16(Ast[c & 1][ki], b2, acc[2], 0, 0, 0);
            }
        }
        if (c + 1 < NCH) {
            if (c + 2 < NCH) loadW(c + 2, Wst[c & 1]);
            writeW(c + 1, Wst[(c + 1) & 1], (c + 1) & 1);
            __syncthreads();
        }
    }

    int j = jb + l15;
    float bir = biasf[3072 + j], biz = biasf[3584 + j], bin = biasf[4096 + j];
    float bhr = biasf[4608 + j], bhz = biasf[5120 + j], bhn = biasf[5632 + j];
#pragma unroll
    for (int r = 0; r < 4; r++) {
        int m = mw + quad * 4 + r;
        if (m >= M2) continue;
        float dr = acc[0][r] + bir;
        float dz = acc[1][r] + biz;
        float dn = acc[2][r] + bin;
        if (m < n) {
            float rr = sigm(dr + bhr);
            float zz = sigm(dz + bhz);
            float nn = tanh_f(dn + rr * bhn);
            float h = (1.0f - zz) * nn;
            h1b[(size_t)m * MEM + j] = f2b(h);
            if (h1f) h1f[(size_t)m * MEM + j] = h;
        } else {
            int mr = m - n;
            gi_r[(size_t)mr * 1536 + j] = dr;
            gi_r[(size_t)mr * 1536 + 512 + j] = dz;
            gi_r[(size_t)mr * 1536 + 1024 + j] = dn;
        }
    }
}

// midB/midC share a frame: gh = A@W (K=512) + combine.
// MODE 0 = midB (gi from gi_r, hp = h1), MODE 1 = midC (gi = node_bi, hp = h2).
template<int MODE>
__launch_bounds__(256, 2)
__global__ void midBC(const unsigned short* __restrict__ Ab,     // h1b / h2b
                      const float* __restrict__ Af,              // h1f / h2f
                      const unsigned short* __restrict__ W,      // Whc / Whn
                      const float* __restrict__ biasf,
                      const float* __restrict__ gi_r,
                      int n,
                      unsigned short* __restrict__ outb,
                      float* __restrict__ outf) {
    constexpr int NCH = 4;
    int tid = threadIdx.x;
    int w = tid >> 6, lane = tid & 63, l15 = lane & 15, quad = lane >> 4;
    int Nm = (n + 63) >> 6;
    int mb, j16;
    mid_map(blockIdx.x, Nm, mb, j16);
    int jb = j16 * 16;
    int mw = mb * 64 + w * 16;

    __shared__ unsigned short lds[2][48 * LP];

    auto loadW = [&](int c, short8* wrg) {
        int kc = tid & 15;
#pragma unroll
        for (int p = 0; p < 3; p++) {
            int row = (tid >> 4) + p * 16;
            int gate = row >> 4, jj = row & 15;
            wrg[p] = *(const short8*)(W + (size_t)(gate * 512 + jb + jj) * MEM + c * 128 + kc * 8);
        }
    };
    auto writeW = [&](const short8* wrg, int buf) {
        int kc = tid & 15;
#pragma unroll
        for (int p = 0; p < 3; p++) {
            int row = (tid >> 4) + p * 16;
            *(short8*)(&lds[buf][row * LP + kc * 8]) = wrg[p];
        }
    };
    auto loadA = [&](int c, short8* ar) {
        int row = mw + l15;
        if (row >= n) row = n - 1;
#pragma unroll
        for (int ki = 0; ki < 4; ki++)
            ar[ki] = *(const short8*)(Ab + (size_t)row * MEM + c * 128 + quad * 8 + ki * 32);
    };

    floatx4 acc[3];
#pragma unroll
    for (int g = 0; g < 3; g++) acc[g] = (floatx4){0.f, 0.f, 0.f, 0.f};

    short8 Wst[2][3];
    short8 Ast[2][4];

    loadW(0, Wst[0]);
    writeW(Wst[0], 0);
    loadW(1, Wst[1]);
    loadA(0, Ast[0]);
    __syncthreads();

#pragma unroll
    for (int c = 0; c < NCH; c++) {
        if (c + 1 < NCH) loadA(c + 1, Ast[(c + 1) & 1]);
        const unsigned short* lb = &lds[c & 1][l15 * LP + quad * 8];
#pragma unroll
        for (int ki = 0; ki < 4; ki++) {
            short8 b0 = *(const short8*)(lb + ki * 32);
            short8 b1 = *(const short8*)(lb + 16 * LP + ki * 32);
            short8 b2 = *(const short8*)(lb + 32 * LP + ki * 32);
            acc[0] = __builtin_amdgcn_mfma_f32_16x16x32_bf16(Ast[c & 1][ki], b0, acc[0], 0, 0, 0);
            acc[1] = __builtin_amdgcn_mfma_f32_16x16x32_bf16(Ast[c & 1][ki], b1, acc[1], 0, 0, 0);
            acc[2] = __builtin_amdgcn_mfma_f32_16x16x32_bf16(Ast[c & 1][ki], b2, acc[2], 0, 0, 0);
        }
        if (c + 1 < NCH) {
            if (c + 2 < NCH) loadW(c + 2, Wst[c & 1]);
            writeW(Wst[(c + 1) & 1], (c + 1) & 1);
            __syncthreads();
        }
    }

    int j = jb + l15;
    if (MODE == 0) {
        float bhr = biasf[4608 + j], bhz = biasf[5120 + j], bhn = biasf[5632 + j];
#pragma unroll
        for (int r = 0; r < 4; r++) {
            int m = mw + quad * 4 + r;
            if (m >= n) continue;
            float gi0 = gi_r[(size_t)m * 1536 + j];
            float gi1 = gi_r[(size_t)m * 1536 + 512 + j];
            float gi2 = gi_r[(size_t)m * 1536 + 1024 + j];
            float hp = Af ? Af[(size_t)m * MEM + j] : b2f(Ab[(size_t)m * MEM + j]);
            float rr = sigm(gi0 + acc[0][r] + bhr);
            float zz = sigm(gi1 + acc[1][r] + bhz);
            float nn = tanh_f(gi2 + rr * (acc[2][r] + bhn));
            float h = (1.0f - zz) * nn + zz * hp;
            outb[(size_t)m * MEM + j] = f2b(h);
            if (outf) outf[(size_t)m * MEM + j] = h;
        }
    } else {
        float gir = biasf[6144 + j], giz = biasf[6656 + j], gin = biasf[7168 + j];
        float bhr = biasf[7680 + j], bhz = biasf[8192 + j], bhn = biasf[8704 + j];
#pragma unroll
        for (int r = 0; r < 4; r++) {
            int m = mw + quad * 4 + r;
            if (m >= n) continue;
            float hp = Af ? Af[(size_t)m * MEM + j] : b2f(Ab[(size_t)m * MEM + j]);
            float rr = sigm(gir + acc[0][r] + bhr);
            float zz = sigm(giz + acc[1][r] + bhz);
            float nn = tanh_f(gin + rr * (acc[2][r] + bhn));
            float h = (1.0f - zz) * nn + zz * hp;
            outb[(size_t)m * MEM + j] = f2b(h);
            if (outf) outf[(size_t)m * MEM + j] = h;
        }
    }
}

__global__ void copy_out_kernel(const int* __restrict__ flag,
                                const unsigned short* __restrict__ states,
                                const float* __restrict__ rootf,
                                void* __restrict__ out) {
    int j = threadIdx.x;
    if (j >= MEM) return;
    if (*flag) ((float*)out)[j] = rootf[j];
    else ((unsigned short*)out)[j] = states[j];
}

// ---------------- launch ----------------

extern "C" void kernel_launch(void* const* d_in, const int* in_sizes, int n_in,
                              void* d_out, int out_size, void* d_ws, size_t ws_size,
                              hipStream_t stream) {
    const void* embs    = d_in[0];
    const void* tags    = d_in[1];
    const void* leaf_Wi = d_in[2];
    const void* leaf_bi = d_in[4];
    const void* leaf_bh = d_in[5];
    const void* node_Wh = d_in[7];
    const void* node_bi = d_in[8];
    const void* node_bh = d_in[9];
    const void* ch_Wi   = d_in[10];
    const void* ch_Wh   = d_in[11];
    const void* ch_bi   = d_in[12];
    const void* ch_bh   = d_in[13];
    (void)in_sizes; (void)n_in; (void)out_size;

    char* ws = (char*)d_ws;
    const size_t o_flag   = 0;
    const size_t o_bias   = 256;
    const size_t o_Wl     = o_bias + 36864;
    const size_t o_Wc     = o_Wl + (size_t)1536 * KP_LEAF * 2;
    const size_t o_Whc    = o_Wc + (size_t)1536 * KP_CH * 2;
    const size_t o_Whn    = o_Whc + (size_t)1536 * MEM * 2;
    const size_t o_states = o_Whn + (size_t)1536 * MEM * 2;
    const size_t o_T2     = o_states + (size_t)32768 * MEM * 2;
    const size_t o_h1b    = o_T2 + (size_t)32768 * T2W * 2;
    const size_t o_h2b    = o_h1b + (size_t)8192 * MEM * 2;
    const size_t o_rootf  = o_h2b + (size_t)8192 * MEM * 2;
    const size_t o_h1f    = o_rootf + 2048;
    const size_t o_h2f    = o_h1f + (size_t)8192 * MEM * 4;
    const size_t NEED0    = o_h2f + (size_t)8192 * MEM * 4;   // ~105 MB

    bool tier0 = (ws_size >= NEED0);

    int*            flag   = (int*)(ws + o_flag);
    float*          biasf  = (float*)(ws + o_bias);
    unsigned short* Wl     = (unsigned short*)(ws + o_Wl);
    unsigned short* Wc     = (unsigned short*)(ws + o_Wc);
    unsigned short* Whc    = (unsigned short*)(ws + o_Whc);
    unsigned short* Whn    = (unsigned short*)(ws + o_Whn);
    unsigned short* states = (unsigned short*)(ws + o_states);
    unsigned short* T2all  = (unsigned short*)(ws + o_T2);
    unsigned short* h1b    = (unsigned short*)(ws + o_h1b);
    unsigned short* h2b    = (unsigned short*)(ws + o_h2b);
    float*          rootf  = (float*)(ws + o_rootf);
    float*          h1f    = tier0 ? (float*)(ws + o_h1f) : nullptr;
    float*          h2f    = tier0 ? (float*)(ws + o_h2f) : nullptr;
    // Xleaf overlays h1b+h2b (dead before lvl-13 stage1)
    unsigned short* Xleaf  = (unsigned short*)(ws + o_h1b);
    // gi_r (<=1024 rows x 1536 f32 = 6.29 MB) overlays upper h2b region:
    // h2b uses rows < 1024 (1 MB) when n<=1024; gi_r at +2 MB fits in 8.39 MB.
    float*          gi_r   = (float*)(ws + o_h2b + (size_t)2 * 1024 * 1024);

    init_kernel<<<1, 64, 0, stream>>>(flag);
    detect_kernel<<<256, 256, 0, stream>>>((const unsigned short*)embs, flag);
    prep_kernel<<<2048, 256, 0, stream>>>(flag, embs, tags,
                                          leaf_Wi, ch_Wi, ch_Wh, node_Wh,
                                          leaf_bi, leaf_bh, ch_bi, ch_bh,
                                          node_bi, node_bh,
                                          Wl, Wc, Whc, Whn, biasf, T2all, Xleaf);

    big3<0><<<(LEAVES / 64) * 8, 256, 0, stream>>>(
        states, T2all, Xleaf, Wl, Wc, Whc, Whn, h1b, h1f, h2b, h2f, biasf,
        LEAVES, states + (size_t)(LEAVES - 1) * MEM, nullptr);

#define LAUNCH_BIG3(M, OB, OF) \
    big3<M><<<(n / 64) * 8, 256, 0, stream>>>( \
        states, T2l, nullptr, Wl, Wc, Whc, Whn, h1b, h1f, h2b, h2f, biasf, n, OB, OF)

    for (int lvl = TREE_DEPTH - 1; lvl >= 0; lvl--) {
        int n = 1 << lvl;
        const unsigned short* T2l = T2all + (size_t)(32768 - 4 * n) * T2W;
        unsigned short* st_out = states + (size_t)(n - 1) * MEM;

        if (n >= 2048) {
            LAUNCH_BIG3(1, h1b, h1f);
            LAUNCH_BIG3(2, h2b, h2f);
            LAUNCH_BIG3(3, st_out, nullptr);
        } else {
            int NmA = (2 * n + 63) / 64;
            int NmB = (n + 63) / 64;
            midA<<<NmA * 32, 256, 0, stream>>>(states, T2l, Wc, biasf, n,
                                               h1b, h1f, gi_r);
            midBC<0><<<NmB * 32, 256, 0, stream>>>(h1b, h1f, Whc, biasf, gi_r, n,
                                                   h2b, h2f);
            midBC<1><<<NmB * 32, 256, 0, stream>>>(h2b, h2f, Whn, biasf, nullptr, n,
                                                   st_out, (n == 1) ? rootf : nullptr);
        }
    }

    copy_out_kernel<<<1, 512, 0, stream>>>(flag, states, rootf, d_out);
}